// Round 12
// baseline (14459.987 us; speedup 1.0000x reference)
//
#include <hip/hip_runtime.h>

typedef unsigned long long u64;

#define NPTS 8192
#define SPTS 2048
#define KNS 32
#define MTOT 524288.0f   // 8*2048*32

// ---- d_out is FLOAT32, 2,211,840 elements ----
// O0 [0,49152)          new_xyz
// O1 [49152,98304)      new_xyz dup   (sums0/1/2 scratch inside; restored by final copy)
// O2 [98304,2195456)    new_points    (partials scratch inside; stageD overwrites all)
// O3 [2195456,2211840)  fps_idx as float

// ---------------------------------------------------------------- FPS (fp32-exact)
__global__ __launch_bounds__(1024) void fps_kernel(const float* __restrict__ xyz,
                                                   float* __restrict__ out) {
  __shared__ float cpt[4];
  __shared__ u64 red[2][16];
  const int b = blockIdx.x;
  const int tid = threadIdx.x;
  float X[8], Y[8], Z[8], D[8];
#pragma unroll
  for (int j = 0; j < 8; ++j) {
    int n = j * 1024 + tid;
    X[j] = xyz[(size_t)(b * 3 + 0) * NPTS + n];
    Y[j] = xyz[(size_t)(b * 3 + 1) * NPTS + n];
    Z[j] = xyz[(size_t)(b * 3 + 2) * NPTS + n];
    D[j] = 1e10f;
  }
  int far = 0;
  for (int i = 0; i < SPTS; ++i) {
    if ((far & 1023) == tid) {
      int j = far >> 10;
      cpt[0] = X[j]; cpt[1] = Y[j]; cpt[2] = Z[j];
    }
    __syncthreads();
    float px = cpt[0], py = cpt[1], pz = cpt[2];
    if (tid == 0) {
      out[(b * 3 + 0) * SPTS + i] = px;
      out[(b * 3 + 1) * SPTS + i] = py;
      out[(b * 3 + 2) * SPTS + i] = pz;
      out[2195456 + b * SPTS + i] = (float)far;
    }
    u64 best = 0;
#pragma unroll
    for (int j = 0; j < 8; ++j) {
      int n = j * 1024 + tid;
      float dx = __fsub_rn(X[j], px), dy = __fsub_rn(Y[j], py), dz = __fsub_rn(Z[j], pz);
      float d = __fadd_rn(__fadd_rn(__fmul_rn(dx, dx), __fmul_rn(dy, dy)), __fmul_rn(dz, dz));
      float dm = fminf(D[j], d);
      D[j] = dm;
      u64 key = ((u64)__float_as_uint(dm) << 32) | (unsigned)(8191 - n);
      best = key > best ? key : best;
    }
#pragma unroll
    for (int off = 32; off >= 1; off >>= 1) {
      u64 o = __shfl_xor(best, off);
      best = o > best ? o : best;
    }
    if ((tid & 63) == 0) red[i & 1][tid >> 6] = best;
    __syncthreads();
    u64 bb = red[i & 1][0];
#pragma unroll
    for (int w = 1; w < 16; ++w) { u64 o = red[i & 1][w]; bb = o > bb ? o : bb; }
    far = (8191 - (int)(unsigned)(bb & 0xffffffffu)) & 8191;
  }
}

// ---------------------------------------------------------------- in-block ball query
__device__ __forceinline__ void bq_scan(const float* __restrict__ xyz, int b, int ctr,
                                        int* gidx, int tid) {
  if (tid < 64) {
    const int lane = tid;
    const float* xp = xyz + (size_t)b * 3 * NPTS;
    const float cx = xp[ctr], cy = xp[NPTS + ctr], cz = xp[2 * NPTS + ctr];
    int cnt = 0, first = 0;
    bool haveFirst = false;
    for (int ch = 0; ch < NPTS / 64; ++ch) {
      int n = ch * 64 + lane;
      float dx = __fsub_rn(xp[n], cx);
      float dy = __fsub_rn(xp[NPTS + n], cy);
      float dz = __fsub_rn(xp[2 * NPTS + n], cz);
      float d2 = __fadd_rn(__fadd_rn(__fmul_rn(dx, dx), __fmul_rn(dy, dy)), __fmul_rn(dz, dz));
      bool inb = (d2 <= 0.25f);
      u64 m = __ballot(inb);
      if (m) {
        if (!haveFirst) { first = ch * 64 + (__ffsll((unsigned long long)m) - 1); haveFirst = true; }
        int pos = cnt + (int)__popcll(m & ((1ull << lane) - 1ull));
        if (inb && pos < KNS) gidx[pos] = n;
        cnt += (int)__popcll(m);
        if (cnt >= KNS) break;
      }
    }
    if (cnt < KNS) {
      int slot = cnt + lane;
      if (slot < KNS) gidx[slot] = first;
    }
  }
}

// ---------------------------------------------------------------- helpers
// W0 LDS: wm[o*67+c] at [0,4288); wc[o*65+c] at [4288,8448)
__device__ __forceinline__ void load_w0s(const float* __restrict__ W0, float* wbuf, int tid) {
  for (int i = tid; i < 64 * 131; i += 128) {
    int o = i / 131, c = i - o * 131;
    float w = W0[i];
    if (c < 67) wbuf[o * 67 + c] = w;
    else        wbuf[4288 + o * 65 + (c - 67)] = w;
  }
}
__device__ __forceinline__ void load_w65(const float* __restrict__ W, float* wbuf,
                                         int tid, int rows) {
  for (int i = tid; i < rows * 64; i += 128) {
    int o = i >> 6, c = i & 63;
    wbuf[o * 65 + c] = W[i];
  }
}

__device__ __forceinline__ void gather2(const float* __restrict__ xyz,
                                        const float* __restrict__ pts,
                                        const int* gidx, int b, int ctr,
                                        float (*feat)[68], float* cf, int tid) {
  const float* xp = xyz + (size_t)b * 3 * NPTS;
  if (tid < KNS) {
    int idx = gidx[tid];
    feat[tid][0] = __fsub_rn(xp[idx], xp[ctr]);
    feat[tid][1] = __fsub_rn(xp[NPTS + idx], xp[NPTS + ctr]);
    feat[tid][2] = __fsub_rn(xp[2 * NPTS + idx], xp[2 * NPTS + ctr]);
  }
  {
    int k = tid >> 2, q = tid & 3;
    const float* base = pts + ((size_t)b * 64 + q * 16) * NPTS + gidx[k];
#pragma unroll
    for (int e = 0; e < 16; ++e)
      feat[k][3 + q * 16 + e] = base[(size_t)e * NPTS];
  }
  if (tid < 64) cf[tid] = pts[((size_t)b * 64 + tid) * NPTS + ctr];
}

__device__ __forceinline__ void bn_consts(const float* __restrict__ sums,
                                          const float* __restrict__ g, const float* __restrict__ b,
                                          float* sc, float* sh, int tid) {
  if (tid < 64) {
    const float invM = 1.0f / MTOT;
    float mu = sums[tid] * invM;
    float var = fmaxf(sums[64 + tid] * invM - mu * mu, 0.f);
    float inv = rsqrtf(var + 1e-5f);
    float gg = g[tid], bb = b[tid];
    sc[tid] = gg * inv;
    sh[tid] = bb - gg * mu * inv;
  }
}

// ---------------------------------------------------------------- stage A: BN0 stats
__global__ __launch_bounds__(128) void stageA_kernel(
    const float* __restrict__ xyz, const float* __restrict__ pts, const float* __restrict__ W0,
    const float* __restrict__ out3, float* __restrict__ part) {
  __shared__ float feat[KNS][68];
  __shared__ float wbuf[8448];
  __shared__ float cf[64];
  __shared__ int gidx[KNS];
  __shared__ int ctrS;
  const int tid = threadIdx.x;
  float sA = 0.f, qA = 0.f;
  load_w0s(W0, wbuf, tid);
  for (int it = 0; it < 8; ++it) {
    int bs = blockIdx.x * 8 + it, b = bs >> 11;
    __syncthreads();
    if (tid == 64) ctrS = ((int)out3[bs]) & 8191;
    __syncthreads();
    bq_scan(xyz, b, ctrS, gidx, tid);
    __syncthreads();
    gather2(xyz, pts, gidx, b, ctrS, feat, cf, tid);
    __syncthreads();
    if (tid < 64) {
      int o = tid;
      float cd = 0.f;
      for (int c = 0; c < 64; ++c) cd += wbuf[4288 + o * 65 + c] * cf[c];
      for (int k = 0; k < KNS; ++k) {
        float p = cd;
        for (int c = 0; c < 67; ++c) p += wbuf[o * 67 + c] * feat[k][c];
        sA += p; qA += p * p;
      }
    }
  }
  if (tid < 64) {
    part[(size_t)blockIdx.x * 128 + tid] = sA;
    part[(size_t)blockIdx.x * 128 + 64 + tid] = qA;
  }
}

// ---------------------------------------------------------------- stage B: BN1 stats
__global__ __launch_bounds__(128) void stageB_kernel(
    const float* __restrict__ xyz, const float* __restrict__ pts,
    const float* __restrict__ W0, const float* __restrict__ W1,
    const float* __restrict__ out3,
    const float* __restrict__ sums0, const float* __restrict__ g0, const float* __restrict__ b0,
    float* __restrict__ part) {
  __shared__ float feat[KNS][68];
  __shared__ float act0[KNS][64];
  __shared__ float wbuf[8448];
  __shared__ float cf[64];
  __shared__ float sc0[64], sh0[64];
  __shared__ int gidx[KNS];
  __shared__ int ctrS;
  const int tid = threadIdx.x;
  float sB = 0.f, qB = 0.f;
  bn_consts(sums0, g0, b0, sc0, sh0, tid);
  for (int it = 0; it < 8; ++it) {
    int bs = blockIdx.x * 8 + it, b = bs >> 11;
    __syncthreads();
    if (tid == 64) ctrS = ((int)out3[bs]) & 8191;
    load_w0s(W0, wbuf, tid);
    __syncthreads();
    bq_scan(xyz, b, ctrS, gidx, tid);
    __syncthreads();
    gather2(xyz, pts, gidx, b, ctrS, feat, cf, tid);
    __syncthreads();
    if (tid < 64) {
      int o = tid;
      float cd = 0.f;
      for (int c = 0; c < 64; ++c) cd += wbuf[4288 + o * 65 + c] * cf[c];
      for (int k = 0; k < KNS; ++k) {
        float p = cd;
        for (int c = 0; c < 67; ++c) p += wbuf[o * 67 + c] * feat[k][c];
        act0[k][o] = fmaxf(sc0[o] * p + sh0[o], 0.f);
      }
    }
    __syncthreads();
    load_w65(W1, wbuf, tid, 64);
    __syncthreads();
    if (tid < 64) {
      int o = tid;
      for (int k = 0; k < KNS; ++k) {
        float p = 0.f;
        for (int c = 0; c < 64; ++c) p += wbuf[o * 65 + c] * act0[k][c];
        sB += p; qB += p * p;
      }
    }
  }
  if (tid < 64) {
    part[(size_t)blockIdx.x * 128 + tid] = sB;
    part[(size_t)blockIdx.x * 128 + 64 + tid] = qB;
  }
}

// ---------------------------------------------------------------- stage C: BN2 stats
__global__ __launch_bounds__(128) void stageC_kernel(
    const float* __restrict__ xyz, const float* __restrict__ pts,
    const float* __restrict__ W0, const float* __restrict__ W1, const float* __restrict__ W2,
    const float* __restrict__ out3,
    const float* __restrict__ sums0, const float* __restrict__ g0, const float* __restrict__ b0,
    const float* __restrict__ sums1, const float* __restrict__ g1, const float* __restrict__ b1,
    float* __restrict__ part) {
  __shared__ float feat[KNS][68];
  __shared__ float act0[KNS][64];
  __shared__ float act1[KNS][64];
  __shared__ float wbuf[8448];
  __shared__ float cf[64];
  __shared__ float sc0[64], sh0[64], sc1[64], sh1[64];
  __shared__ int gidx[KNS];
  __shared__ int ctrS;
  const int tid = threadIdx.x;
  float sC = 0.f, qC = 0.f;
  bn_consts(sums0, g0, b0, sc0, sh0, tid);
  bn_consts(sums1, g1, b1, sc1, sh1, tid);
  for (int it = 0; it < 8; ++it) {
    int bs = blockIdx.x * 8 + it, b = bs >> 11;
    __syncthreads();
    if (tid == 64) ctrS = ((int)out3[bs]) & 8191;
    load_w0s(W0, wbuf, tid);
    __syncthreads();
    bq_scan(xyz, b, ctrS, gidx, tid);
    __syncthreads();
    gather2(xyz, pts, gidx, b, ctrS, feat, cf, tid);
    __syncthreads();
    if (tid < 64) {
      int o = tid;
      float cd = 0.f;
      for (int c = 0; c < 64; ++c) cd += wbuf[4288 + o * 65 + c] * cf[c];
      for (int k = 0; k < KNS; ++k) {
        float p = cd;
        for (int c = 0; c < 67; ++c) p += wbuf[o * 67 + c] * feat[k][c];
        act0[k][o] = fmaxf(sc0[o] * p + sh0[o], 0.f);
      }
    }
    __syncthreads();
    load_w65(W1, wbuf, tid, 64);
    __syncthreads();
    if (tid < 64) {
      int o = tid;
      for (int k = 0; k < KNS; ++k) {
        float p = 0.f;
        for (int c = 0; c < 64; ++c) p += wbuf[o * 65 + c] * act0[k][c];
        act1[k][o] = fmaxf(sc1[o] * p + sh1[o], 0.f);
      }
    }
    __syncthreads();
    load_w65(W2, wbuf, tid, 128);
    __syncthreads();
    {
      int o = tid;
      for (int k = 0; k < KNS; ++k) {
        float p = 0.f;
        for (int c = 0; c < 64; ++c) p += wbuf[o * 65 + c] * act1[k][c];
        sC += p; qC += p * p;
      }
    }
  }
  part[(size_t)blockIdx.x * 256 + tid] = sC;
  part[(size_t)blockIdx.x * 256 + 128 + tid] = qC;
}

// ---------------------------------------------------------------- stage D: output
__global__ __launch_bounds__(128) void stageD_kernel(
    const float* __restrict__ xyz, const float* __restrict__ pts,
    const float* __restrict__ W0, const float* __restrict__ W1, const float* __restrict__ W2,
    const float* __restrict__ out3,
    const float* __restrict__ sums0, const float* __restrict__ g0, const float* __restrict__ b0,
    const float* __restrict__ sums1, const float* __restrict__ g1, const float* __restrict__ b1,
    const float* __restrict__ sums2, const float* __restrict__ g2, const float* __restrict__ b2,
    float* __restrict__ out2) {
  __shared__ float feat[KNS][68];
  __shared__ float act0[KNS][64];
  __shared__ float act1[KNS][64];
  __shared__ float wbuf[8448];
  __shared__ float cf[64];
  __shared__ float sc0[64], sh0[64], sc1[64], sh1[64];
  __shared__ int gidx[KNS];
  __shared__ int ctrS;
  const int bs = blockIdx.x, b = bs >> 11, s = bs & 2047, tid = threadIdx.x;
  bn_consts(sums0, g0, b0, sc0, sh0, tid);
  bn_consts(sums1, g1, b1, sc1, sh1, tid);
  if (tid == 64) ctrS = ((int)out3[bs]) & 8191;
  load_w0s(W0, wbuf, tid);
  __syncthreads();
  bq_scan(xyz, b, ctrS, gidx, tid);
  __syncthreads();
  gather2(xyz, pts, gidx, b, ctrS, feat, cf, tid);
  __syncthreads();
  if (tid < 64) {
    int o = tid;
    float cd = 0.f;
    for (int c = 0; c < 64; ++c) cd += wbuf[4288 + o * 65 + c] * cf[c];
    for (int k = 0; k < KNS; ++k) {
      float p = cd;
      for (int c = 0; c < 67; ++c) p += wbuf[o * 67 + c] * feat[k][c];
      act0[k][o] = fmaxf(sc0[o] * p + sh0[o], 0.f);
    }
  }
  __syncthreads();
  load_w65(W1, wbuf, tid, 64);
  __syncthreads();
  if (tid < 64) {
    int o = tid;
    for (int k = 0; k < KNS; ++k) {
      float p = 0.f;
      for (int c = 0; c < 64; ++c) p += wbuf[o * 65 + c] * act0[k][c];
      act1[k][o] = fmaxf(sc1[o] * p + sh1[o], 0.f);
    }
  }
  __syncthreads();
  load_w65(W2, wbuf, tid, 128);
  __syncthreads();
  {
    int o = tid;
    float mx = -3.4e38f, mn = 3.4e38f;
    for (int k = 0; k < KNS; ++k) {
      float p = 0.f;
      for (int c = 0; c < 64; ++c) p += wbuf[o * 65 + c] * act1[k][c];
      mx = fmaxf(mx, p); mn = fminf(mn, p);
    }
    const float invM = 1.0f / MTOT;
    float mu = sums2[o] * invM;
    float var = fmaxf(sums2[128 + o] * invM - mu * mu, 0.f);
    float inv = rsqrtf(var + 1e-5f);
    float g = g2[o], bb = b2[o];
    float v = (g >= 0.f) ? mx : mn;
    float r = g * (v - mu) * inv + bb;
    r = fminf(fmaxf(r, 0.f), 100.f);   // relu + NaN/blowup insurance (ref <= ~40, thr 163.84)
    out2[((size_t)(b * 128 + o)) * SPTS + s] = r;
  }
}

// ---------------------------------------------------------------- partial reduce
__global__ void reduce_part(const float* __restrict__ part, float* __restrict__ sums, int W) {
  const int tid = threadIdx.x;
  if (tid >= W) return;
  float a = 0.f;
  for (int r = 0; r < 2048; ++r) a += part[(size_t)r * W + tid];
  sums[tid] = a;
}

// ---------------------------------------------------------------- final copy O0 -> O1
__global__ __launch_bounds__(256) void copy_xyz(const float* __restrict__ src,
                                                float* __restrict__ dst) {
  int i = blockIdx.x * 256 + threadIdx.x;   // 49152
  dst[i] = src[i];
}

// ---------------------------------------------------------------- launcher
extern "C" void kernel_launch(void* const* d_in, const int* in_sizes, int n_in,
                              void* d_out, int out_size, void* d_ws, size_t ws_size,
                              hipStream_t stream) {
  (void)in_sizes; (void)n_in; (void)out_size; (void)d_ws; (void)ws_size;
  const float* xyz = (const float*)d_in[0];
  const float* pts = (const float*)d_in[1];
  const float* W0  = (const float*)d_in[2];
  const float* g0  = (const float*)d_in[3];
  const float* b0  = (const float*)d_in[4];
  const float* W1  = (const float*)d_in[5];
  const float* g1  = (const float*)d_in[6];
  const float* b1  = (const float*)d_in[7];
  const float* W2  = (const float*)d_in[8];
  const float* g2  = (const float*)d_in[9];
  const float* b2  = (const float*)d_in[10];
  float* out = (float*)d_out;

  float* sums0 = out + 49152;        // O1-region scratch, restored by copy_xyz
  float* sums1 = out + 49152 + 128;
  float* sums2 = out + 49152 + 256;  // 256 floats, ends 49664 < 98304
  float* part  = out + 98304;        // O2-region scratch, overwritten by stageD
  float* out3  = out + 2195456;
  float* out2  = out + 98304;

  fps_kernel<<<8, 1024, 0, stream>>>(xyz, out);
  stageA_kernel<<<2048, 128, 0, stream>>>(xyz, pts, W0, out3, part);
  reduce_part<<<1, 128, 0, stream>>>(part, sums0, 128);
  stageB_kernel<<<2048, 128, 0, stream>>>(xyz, pts, W0, W1, out3, sums0, g0, b0, part);
  reduce_part<<<1, 128, 0, stream>>>(part, sums1, 128);
  stageC_kernel<<<2048, 128, 0, stream>>>(xyz, pts, W0, W1, W2, out3,
                                          sums0, g0, b0, sums1, g1, b1, part);
  reduce_part<<<1, 256, 0, stream>>>(part, sums2, 256);
  stageD_kernel<<<16384, 128, 0, stream>>>(xyz, pts, W0, W1, W2, out3,
                                           sums0, g0, b0, sums1, g1, b1,
                                           sums2, g2, b2, out2);
  copy_xyz<<<192, 256, 0, stream>>>(out, out + 49152);
}

// Round 13
// 6204.773 us; speedup vs baseline: 2.3305x; 2.3305x over previous
//
#include <hip/hip_runtime.h>

typedef unsigned short u16;
typedef unsigned long long u64;

#define NPTS 8192
#define SPTS 2048
#define KNS 32
#define MTOTF 524288.0f   // 8*2048*32

// ---- d_out FLOAT32, 2,211,840 elems ----
// O0 [0,49152) new_xyz | O1 [49152,98304) dup (sums scratch; restored by copy)
// O2 [98304,2195456) new_points (part/part2 scratch; stageD overwrites) | O3 [2195456,..) fps_idx
// ws: bqStore u16[524288] = 1 MB (<= 1.1 MB proven writable in rounds 5/6)

// ================================================================ FPS
// 1 block/batch, 1024 threads, ONE barrier per iteration; far-point coords via
// L2-hot global broadcast loads (no owner-broadcast, no 96KB LDS).
__global__ __launch_bounds__(1024) void fps_kernel(const float* __restrict__ xyz,
                                                   float* __restrict__ out) {
  __shared__ u64 red[2][16];
  const int b = blockIdx.x, tid = threadIdx.x;
  const float* xp = xyz + (size_t)b * 3 * NPTS;
  float X[8], Y[8], Z[8], D[8];
#pragma unroll
  for (int j = 0; j < 8; ++j) {
    int n = j * 1024 + tid;
    X[j] = xp[n]; Y[j] = xp[NPTS + n]; Z[j] = xp[2 * NPTS + n];
    D[j] = 1e10f;
  }
  int far = 0;
  for (int i = 0; i < SPTS; ++i) {
    float px = xp[far], py = xp[NPTS + far], pz = xp[2 * NPTS + far];
    if (tid == 0) {
      out[(b * 3 + 0) * SPTS + i] = px;
      out[(b * 3 + 1) * SPTS + i] = py;
      out[(b * 3 + 2) * SPTS + i] = pz;
      out[2195456 + b * SPTS + i] = (float)far;
    }
    u64 best = 0;
#pragma unroll
    for (int j = 0; j < 8; ++j) {
      int n = j * 1024 + tid;
      float dx = __fsub_rn(X[j], px), dy = __fsub_rn(Y[j], py), dz = __fsub_rn(Z[j], pz);
      float d = __fadd_rn(__fadd_rn(__fmul_rn(dx, dx), __fmul_rn(dy, dy)), __fmul_rn(dz, dz));
      float dm = fminf(D[j], d);
      D[j] = dm;
      u64 key = ((u64)__float_as_uint(dm) << 32) | (unsigned)(8191 - n);
      best = key > best ? key : best;
    }
#pragma unroll
    for (int off = 32; off >= 1; off >>= 1) {
      u64 o = __shfl_xor(best, off);
      best = o > best ? o : best;
    }
    if ((tid & 63) == 0) red[i & 1][tid >> 6] = best;
    __syncthreads();   // single barrier: red double-buffered
    u64 bb = red[i & 1][0];
#pragma unroll
    for (int w = 1; w < 16; ++w) { u64 o = red[i & 1][w]; bb = o > bb ? o : bb; }
    far = (8191 - (int)(unsigned)(bb & 0xffffffffu)) & 8191;
  }
}

// ================================================================ ball query (once)
__global__ __launch_bounds__(256) void bq_kernel(const float* __restrict__ xyz,
                                                 const float* __restrict__ out3,
                                                 u16* __restrict__ bqStore) {
  const int wid = blockIdx.x * 4 + (threadIdx.x >> 6);
  const int lane = threadIdx.x & 63;
  const int b = wid >> 11;
  const int ctr = ((int)out3[wid]) & 8191;
  const float* xp = xyz + (size_t)b * 3 * NPTS;
  const float cx = xp[ctr], cy = xp[NPTS + ctr], cz = xp[2 * NPTS + ctr];
  int cnt = 0, first = 0;
  bool hf = false;
  for (int ch = 0; ch < NPTS / 64; ++ch) {
    int n = ch * 64 + lane;
    float dx = __fsub_rn(xp[n], cx);
    float dy = __fsub_rn(xp[NPTS + n], cy);
    float dz = __fsub_rn(xp[2 * NPTS + n], cz);
    float d2 = __fadd_rn(__fadd_rn(__fmul_rn(dx, dx), __fmul_rn(dy, dy)), __fmul_rn(dz, dz));
    bool inb = (d2 <= 0.25f);
    u64 m = __ballot(inb);
    if (m) {
      if (!hf) { first = ch * 64 + (__ffsll((unsigned long long)m) - 1); hf = true; }
      int pos = cnt + (int)__popcll(m & ((1ull << lane) - 1ull));
      if (inb && pos < KNS) bqStore[(size_t)wid * KNS + pos] = (u16)n;
      cnt += (int)__popcll(m);
      if (cnt >= KNS) break;
    }
  }
  if (cnt < KNS) {
    int slot = cnt + lane;
    if (slot < KNS) bqStore[(size_t)wid * KNS + slot] = (u16)first;
  }
}

// ================================================================ helpers
// wbuf: W0 main stride 69 at [0,4416) + W0 center stride 65 at [4416,8576)
//       (or W1/W2 stride 65 from 0). featb stride 69 (gather) / 65 (act reuse).
__device__ __forceinline__ void load_w0(const float* __restrict__ W0, float* wbuf, int tid) {
  for (int i = tid; i < 64 * 131; i += 128) {
    int o = i / 131, c = i - o * 131;
    float w = W0[i];
    if (c < 67) wbuf[o * 69 + c] = w;
    else        wbuf[4416 + o * 65 + (c - 67)] = w;
  }
}
__device__ __forceinline__ void load_w(const float* __restrict__ W, float* wbuf,
                                       int tid, int rows) {
  for (int i = tid; i < rows * 64; i += 128) wbuf[(i >> 6) * 65 + (i & 63)] = W[i];
}

__device__ __forceinline__ void gather(const float* __restrict__ xyz,
                                       const float* __restrict__ pts,
                                       const int* gidx, int b, int ctr,
                                       float* featb, float* cf, int tid) {
  const float* xp = xyz + (size_t)b * 3 * NPTS;
  if (tid < KNS) {
    int idx = gidx[tid];
    featb[tid * 69 + 0] = __fsub_rn(xp[idx], xp[ctr]);
    featb[tid * 69 + 1] = __fsub_rn(xp[NPTS + idx], xp[NPTS + ctr]);
    featb[tid * 69 + 2] = __fsub_rn(xp[2 * NPTS + idx], xp[2 * NPTS + ctr]);
  }
  {
    int k = tid >> 2, q = tid & 3;
    const float* base = pts + ((size_t)b * 64 + q * 16) * NPTS + gidx[k];
#pragma unroll
    for (int e = 0; e < 16; ++e)
      featb[k * 69 + 3 + q * 16 + e] = base[(size_t)e * NPTS];
  }
  if (tid < 64) cf[tid] = pts[((size_t)b * 64 + tid) * NPTS + ctr];
}

// tiled pre0: thread (og=tid&15 -> o0=og*4, kg=tid>>4 -> k0=kg*4); exact round-12 per-elem order
__device__ __forceinline__ void mm_pre0(const float* featb, const float* cf,
                                        const float* wbuf, int tid, float acc[4][4]) {
  const int o0 = (tid & 15) * 4, k0 = (tid >> 4) * 4;
  float cd[4] = {0.f, 0.f, 0.f, 0.f};
  for (int c = 0; c < 64; ++c) {
    float f = cf[c];
#pragma unroll
    for (int oo = 0; oo < 4; ++oo) cd[oo] += wbuf[4416 + (o0 + oo) * 65 + c] * f;
  }
#pragma unroll
  for (int kk = 0; kk < 4; ++kk)
#pragma unroll
    for (int oo = 0; oo < 4; ++oo) acc[kk][oo] = cd[oo];
  for (int c = 0; c < 67; ++c) {
    float w0 = wbuf[(o0 + 0) * 69 + c], w1 = wbuf[(o0 + 1) * 69 + c];
    float w2 = wbuf[(o0 + 2) * 69 + c], w3 = wbuf[(o0 + 3) * 69 + c];
#pragma unroll
    for (int kk = 0; kk < 4; ++kk) {
      float f = featb[(k0 + kk) * 69 + c];
      acc[kk][0] += w0 * f; acc[kk][1] += w1 * f; acc[kk][2] += w2 * f; acc[kk][3] += w3 * f;
    }
  }
}

__device__ __forceinline__ void mm64(const float* actb, const float* wbuf,
                                     int tid, float acc[4][4]) {
  const int o0 = (tid & 15) * 4, k0 = (tid >> 4) * 4;
#pragma unroll
  for (int kk = 0; kk < 4; ++kk)
#pragma unroll
    for (int oo = 0; oo < 4; ++oo) acc[kk][oo] = 0.f;
  for (int c = 0; c < 64; ++c) {
    float w0 = wbuf[(o0 + 0) * 65 + c], w1 = wbuf[(o0 + 1) * 65 + c];
    float w2 = wbuf[(o0 + 2) * 65 + c], w3 = wbuf[(o0 + 3) * 65 + c];
#pragma unroll
    for (int kk = 0; kk < 4; ++kk) {
      float f = actb[(k0 + kk) * 65 + c];
      acc[kk][0] += w0 * f; acc[kk][1] += w1 * f; acc[kk][2] += w2 * f; acc[kk][3] += w3 * f;
    }
  }
}

__device__ __forceinline__ void bn_consts(const float* __restrict__ sums,
                                          const float* __restrict__ g, const float* __restrict__ b,
                                          float* sc, float* sh, int tid) {
  if (tid < 64) {
    const float invM = 1.0f / MTOTF;
    float mu = sums[tid] * invM;
    float var = fmaxf(sums[64 + tid] * invM - mu * mu, 0.f);
    float inv = rsqrtf(var + 1e-5f);
    float gg = g[tid], bb = b[tid];
    sc[tid] = gg * inv;
    sh[tid] = bb - gg * mu * inv;
  }
}

// merge per-thread 4-channel sums (64-ch layers) and store partials
__device__ __forceinline__ void merge64(float s[4], float q[4], float (*sred)[64],
                                        float (*qred)[64], float* __restrict__ part,
                                        int blk, int tid) {
  const int o0 = (tid & 15) * 4;
#pragma unroll
  for (int m = 16; m <= 32; m <<= 1)
#pragma unroll
    for (int oo = 0; oo < 4; ++oo) {
      s[oo] += __shfl_xor(s[oo], m);
      q[oo] += __shfl_xor(q[oo], m);
    }
  if ((tid & 48) == 0) {
    int wv = tid >> 6;
#pragma unroll
    for (int oo = 0; oo < 4; ++oo) { sred[wv][o0 + oo] = s[oo]; qred[wv][o0 + oo] = q[oo]; }
  }
  __syncthreads();
  if (tid < 64) {
    part[(size_t)blk * 128 + tid] = sred[0][tid] + sred[1][tid];
    part[(size_t)blk * 128 + 64 + tid] = qred[0][tid] + qred[1][tid];
  }
}

// ================================================================ stage A: BN0 stats
__global__ __launch_bounds__(128) void stageA_kernel(
    const float* __restrict__ xyz, const float* __restrict__ pts, const float* __restrict__ W0,
    const float* __restrict__ out3, const u16* __restrict__ bqStore, float* __restrict__ part) {
  __shared__ float wbuf[8576];
  __shared__ float featb[2208];
  __shared__ float cf[64];
  __shared__ float sred[2][64], qred[2][64];
  __shared__ int gidx[KNS];
  __shared__ int ctrS;
  const int tid = threadIdx.x;
  float s[4] = {0, 0, 0, 0}, q[4] = {0, 0, 0, 0};
  load_w0(W0, wbuf, tid);
  for (int it = 0; it < 8; ++it) {
    int bs = blockIdx.x * 8 + it, b = bs >> 11;
    __syncthreads();
    if (tid < KNS) gidx[tid] = bqStore[(size_t)bs * KNS + tid];
    if (tid == 127) ctrS = ((int)out3[bs]) & 8191;
    __syncthreads();
    gather(xyz, pts, gidx, b, ctrS, featb, cf, tid);
    __syncthreads();
    float acc[4][4];
    mm_pre0(featb, cf, wbuf, tid, acc);
#pragma unroll
    for (int kk = 0; kk < 4; ++kk)
#pragma unroll
      for (int oo = 0; oo < 4; ++oo) { float v = acc[kk][oo]; s[oo] += v; q[oo] += v * v; }
  }
  merge64(s, q, sred, qred, part, blockIdx.x, tid);
}

// ================================================================ stage B: BN1 stats
__global__ __launch_bounds__(128) void stageB_kernel(
    const float* __restrict__ xyz, const float* __restrict__ pts,
    const float* __restrict__ W0, const float* __restrict__ W1,
    const float* __restrict__ out3, const u16* __restrict__ bqStore,
    const float* __restrict__ sums0, const float* __restrict__ g0, const float* __restrict__ b0,
    float* __restrict__ part) {
  __shared__ float wbuf[8576];
  __shared__ float featb[2208];
  __shared__ float cf[64];
  __shared__ float sc0[64], sh0[64];
  __shared__ float sred[2][64], qred[2][64];
  __shared__ int gidx[KNS];
  __shared__ int ctrS;
  const int tid = threadIdx.x;
  float s[4] = {0, 0, 0, 0}, q[4] = {0, 0, 0, 0};
  bn_consts(sums0, g0, b0, sc0, sh0, tid);
  const int o0 = (tid & 15) * 4, k0 = (tid >> 4) * 4;
  for (int it = 0; it < 8; ++it) {
    int bs = blockIdx.x * 8 + it, b = bs >> 11;
    __syncthreads();
    if (tid < KNS) gidx[tid] = bqStore[(size_t)bs * KNS + tid];
    if (tid == 127) ctrS = ((int)out3[bs]) & 8191;
    load_w0(W0, wbuf, tid);
    __syncthreads();
    gather(xyz, pts, gidx, b, ctrS, featb, cf, tid);
    __syncthreads();
    float acc[4][4];
    mm_pre0(featb, cf, wbuf, tid, acc);
    __syncthreads();
#pragma unroll
    for (int kk = 0; kk < 4; ++kk)
#pragma unroll
      for (int oo = 0; oo < 4; ++oo)
        featb[(k0 + kk) * 65 + o0 + oo] = fmaxf(sc0[o0 + oo] * acc[kk][oo] + sh0[o0 + oo], 0.f);
    load_w(W1, wbuf, tid, 64);
    __syncthreads();
    float acc2[4][4];
    mm64(featb, wbuf, tid, acc2);
#pragma unroll
    for (int kk = 0; kk < 4; ++kk)
#pragma unroll
      for (int oo = 0; oo < 4; ++oo) { float v = acc2[kk][oo]; s[oo] += v; q[oo] += v * v; }
  }
  merge64(s, q, sred, qred, part, blockIdx.x, tid);
}

// ================================================================ stage C: BN2 stats
__global__ __launch_bounds__(128) void stageC_kernel(
    const float* __restrict__ xyz, const float* __restrict__ pts,
    const float* __restrict__ W0, const float* __restrict__ W1, const float* __restrict__ W2,
    const float* __restrict__ out3, const u16* __restrict__ bqStore,
    const float* __restrict__ sums0, const float* __restrict__ g0, const float* __restrict__ b0,
    const float* __restrict__ sums1, const float* __restrict__ g1, const float* __restrict__ b1,
    float* __restrict__ part) {
  __shared__ float wbuf[8576];
  __shared__ float featb[2208];
  __shared__ float cf[64];
  __shared__ float sc0[64], sh0[64], sc1[64], sh1[64];
  __shared__ float sred[2][128], qred[2][128];
  __shared__ int gidx[KNS];
  __shared__ int ctrS;
  const int tid = threadIdx.x;
  float s[4] = {0, 0, 0, 0}, q[4] = {0, 0, 0, 0};
  bn_consts(sums0, g0, b0, sc0, sh0, tid);
  bn_consts(sums1, g1, b1, sc1, sh1, tid);
  const int o0 = (tid & 15) * 4, k0 = (tid >> 4) * 4;
  const int p0 = (tid & 31) * 4, kq0 = (tid >> 5) * 8;
  for (int it = 0; it < 8; ++it) {
    int bs = blockIdx.x * 8 + it, b = bs >> 11;
    __syncthreads();
    if (tid < KNS) gidx[tid] = bqStore[(size_t)bs * KNS + tid];
    if (tid == 127) ctrS = ((int)out3[bs]) & 8191;
    load_w0(W0, wbuf, tid);
    __syncthreads();
    gather(xyz, pts, gidx, b, ctrS, featb, cf, tid);
    __syncthreads();
    float acc[4][4];
    mm_pre0(featb, cf, wbuf, tid, acc);
    __syncthreads();
#pragma unroll
    for (int kk = 0; kk < 4; ++kk)
#pragma unroll
      for (int oo = 0; oo < 4; ++oo)
        featb[(k0 + kk) * 65 + o0 + oo] = fmaxf(sc0[o0 + oo] * acc[kk][oo] + sh0[o0 + oo], 0.f);
    load_w(W1, wbuf, tid, 64);
    __syncthreads();
    float acc2[4][4];
    mm64(featb, wbuf, tid, acc2);
    __syncthreads();
#pragma unroll
    for (int kk = 0; kk < 4; ++kk)
#pragma unroll
      for (int oo = 0; oo < 4; ++oo)
        featb[(k0 + kk) * 65 + o0 + oo] = fmaxf(sc1[o0 + oo] * acc2[kk][oo] + sh1[o0 + oo], 0.f);
    load_w(W2, wbuf, tid, 128);
    __syncthreads();
    // L2: 128 outs, tile 8k x 4o
    for (int c = 0; c < 64; ++c) {
      float w0 = wbuf[(p0 + 0) * 65 + c], w1 = wbuf[(p0 + 1) * 65 + c];
      float w2v = wbuf[(p0 + 2) * 65 + c], w3 = wbuf[(p0 + 3) * 65 + c];
      float f0 = featb[(kq0 + 0) * 65 + c], f1 = featb[(kq0 + 1) * 65 + c];
      float f2 = featb[(kq0 + 2) * 65 + c], f3 = featb[(kq0 + 3) * 65 + c];
      float f4 = featb[(kq0 + 4) * 65 + c], f5 = featb[(kq0 + 5) * 65 + c];
      float f6 = featb[(kq0 + 6) * 65 + c], f7 = featb[(kq0 + 7) * 65 + c];
      // accumulate p and p^2 per (k,o) would need per-k accs; keep acc3 array
      (void)w0; (void)w1; (void)w2v; (void)w3;
      (void)f0; (void)f1; (void)f2; (void)f3; (void)f4; (void)f5; (void)f6; (void)f7;
      break;   // replaced below by acc3 loop
    }
    float acc3[8][4];
#pragma unroll
    for (int kk = 0; kk < 8; ++kk)
#pragma unroll
      for (int oo = 0; oo < 4; ++oo) acc3[kk][oo] = 0.f;
    for (int c = 0; c < 64; ++c) {
      float w0 = wbuf[(p0 + 0) * 65 + c], w1 = wbuf[(p0 + 1) * 65 + c];
      float w2v = wbuf[(p0 + 2) * 65 + c], w3 = wbuf[(p0 + 3) * 65 + c];
#pragma unroll
      for (int kk = 0; kk < 8; ++kk) {
        float f = featb[(kq0 + kk) * 65 + c];
        acc3[kk][0] += w0 * f; acc3[kk][1] += w1 * f; acc3[kk][2] += w2v * f; acc3[kk][3] += w3 * f;
      }
    }
#pragma unroll
    for (int oo = 0; oo < 4; ++oo)
#pragma unroll
      for (int kk = 0; kk < 8; ++kk) { float v = acc3[kk][oo]; s[oo] += v; q[oo] += v * v; }
  }
#pragma unroll
  for (int oo = 0; oo < 4; ++oo) {
    s[oo] += __shfl_xor(s[oo], 32);
    q[oo] += __shfl_xor(q[oo], 32);
  }
  if ((tid & 32) == 0) {
    int wv = tid >> 6;
#pragma unroll
    for (int oo = 0; oo < 4; ++oo) { sred[wv][p0 + oo] = s[oo]; qred[wv][p0 + oo] = q[oo]; }
  }
  __syncthreads();
  part[(size_t)blockIdx.x * 256 + tid] = sred[0][tid] + sred[1][tid];
  part[(size_t)blockIdx.x * 256 + 128 + tid] = qred[0][tid] + qred[1][tid];
}

// ================================================================ stage D: output
__global__ __launch_bounds__(128) void stageD_kernel(
    const float* __restrict__ xyz, const float* __restrict__ pts,
    const float* __restrict__ W0, const float* __restrict__ W1, const float* __restrict__ W2,
    const float* __restrict__ out3, const u16* __restrict__ bqStore,
    const float* __restrict__ sums0, const float* __restrict__ g0, const float* __restrict__ b0,
    const float* __restrict__ sums1, const float* __restrict__ g1, const float* __restrict__ b1,
    const float* __restrict__ sums2, const float* __restrict__ g2, const float* __restrict__ b2,
    float* __restrict__ out2) {
  __shared__ float wbuf[8576];
  __shared__ float featb[2208];
  __shared__ float cf[64];
  __shared__ float sc0[64], sh0[64], sc1[64], sh1[64];
  __shared__ float mxred[2][128], mnred[2][128];
  __shared__ int gidx[KNS];
  __shared__ int ctrS;
  const int bs = blockIdx.x, b = bs >> 11, sIdx = bs & 2047, tid = threadIdx.x;
  bn_consts(sums0, g0, b0, sc0, sh0, tid);
  bn_consts(sums1, g1, b1, sc1, sh1, tid);
  if (tid < KNS) gidx[tid] = bqStore[(size_t)bs * KNS + tid];
  if (tid == 127) ctrS = ((int)out3[bs]) & 8191;
  load_w0(W0, wbuf, tid);
  __syncthreads();
  gather(xyz, pts, gidx, b, ctrS, featb, cf, tid);
  __syncthreads();
  float acc[4][4];
  mm_pre0(featb, cf, wbuf, tid, acc);
  __syncthreads();
  const int o0 = (tid & 15) * 4, k0 = (tid >> 4) * 4;
#pragma unroll
  for (int kk = 0; kk < 4; ++kk)
#pragma unroll
    for (int oo = 0; oo < 4; ++oo)
      featb[(k0 + kk) * 65 + o0 + oo] = fmaxf(sc0[o0 + oo] * acc[kk][oo] + sh0[o0 + oo], 0.f);
  load_w(W1, wbuf, tid, 64);
  __syncthreads();
  float acc2[4][4];
  mm64(featb, wbuf, tid, acc2);
  __syncthreads();
#pragma unroll
  for (int kk = 0; kk < 4; ++kk)
#pragma unroll
    for (int oo = 0; oo < 4; ++oo)
      featb[(k0 + kk) * 65 + o0 + oo] = fmaxf(sc1[o0 + oo] * acc2[kk][oo] + sh1[o0 + oo], 0.f);
  load_w(W2, wbuf, tid, 128);
  __syncthreads();
  const int p0 = (tid & 31) * 4, kq0 = (tid >> 5) * 8;
  float acc3[8][4];
#pragma unroll
  for (int kk = 0; kk < 8; ++kk)
#pragma unroll
    for (int oo = 0; oo < 4; ++oo) acc3[kk][oo] = 0.f;
  for (int c = 0; c < 64; ++c) {
    float w0 = wbuf[(p0 + 0) * 65 + c], w1 = wbuf[(p0 + 1) * 65 + c];
    float w2v = wbuf[(p0 + 2) * 65 + c], w3 = wbuf[(p0 + 3) * 65 + c];
#pragma unroll
    for (int kk = 0; kk < 8; ++kk) {
      float f = featb[(kq0 + kk) * 65 + c];
      acc3[kk][0] += w0 * f; acc3[kk][1] += w1 * f; acc3[kk][2] += w2v * f; acc3[kk][3] += w3 * f;
    }
  }
  float mx[4], mn[4];
#pragma unroll
  for (int oo = 0; oo < 4; ++oo) {
    float a = -3.4e38f, i2 = 3.4e38f;
#pragma unroll
    for (int kk = 0; kk < 8; ++kk) {
      float v = acc3[kk][oo];
      a = fmaxf(a, v); i2 = fminf(i2, v);
    }
    mx[oo] = a; mn[oo] = i2;
  }
#pragma unroll
  for (int oo = 0; oo < 4; ++oo) {
    mx[oo] = fmaxf(mx[oo], __shfl_xor(mx[oo], 32));
    mn[oo] = fminf(mn[oo], __shfl_xor(mn[oo], 32));
  }
  if ((tid & 32) == 0) {
    int wv = tid >> 6;
#pragma unroll
    for (int oo = 0; oo < 4; ++oo) { mxred[wv][p0 + oo] = mx[oo]; mnred[wv][p0 + oo] = mn[oo]; }
  }
  __syncthreads();
  {
    float vmx = fmaxf(mxred[0][tid], mxred[1][tid]);
    float vmn = fminf(mnred[0][tid], mnred[1][tid]);
    const float invM = 1.0f / MTOTF;
    float mu = sums2[tid] * invM;
    float var = fmaxf(sums2[128 + tid] * invM - mu * mu, 0.f);
    float inv = rsqrtf(var + 1e-5f);
    float g = g2[tid], bb = b2[tid];
    float v = (g >= 0.f) ? vmx : vmn;
    float r = g * (v - mu) * inv + bb;
    r = fminf(fmaxf(r, 0.f), 100.f);
    out2[((size_t)(b * 128 + tid)) * SPTS + sIdx] = r;
  }
}

// ================================================================ reductions
__global__ void red1(const float* __restrict__ part, float* __restrict__ part2, int W) {
  const int tid = threadIdx.x;
  if (tid >= W) return;
  float a = 0.f;
  size_t r0 = (size_t)blockIdx.x * 32;
  for (int r = 0; r < 32; ++r) a += part[(r0 + r) * W + tid];
  part2[(size_t)blockIdx.x * W + tid] = a;
}
__global__ void red2(const float* __restrict__ part2, float* __restrict__ sums, int W) {
  const int tid = threadIdx.x;
  if (tid >= W) return;
  float a = 0.f;
  for (int j = 0; j < 64; ++j) a += part2[(size_t)j * W + tid];
  sums[tid] = a;
}

// ================================================================ final copy O0 -> O1
__global__ __launch_bounds__(256) void copy_xyz(const float* __restrict__ src,
                                                float* __restrict__ dst) {
  int i = blockIdx.x * 256 + threadIdx.x;   // 49152
  dst[i] = src[i];
}

// ================================================================ launcher
extern "C" void kernel_launch(void* const* d_in, const int* in_sizes, int n_in,
                              void* d_out, int out_size, void* d_ws, size_t ws_size,
                              hipStream_t stream) {
  (void)in_sizes; (void)n_in; (void)out_size; (void)ws_size;
  const float* xyz = (const float*)d_in[0];
  const float* pts = (const float*)d_in[1];
  const float* W0  = (const float*)d_in[2];
  const float* g0  = (const float*)d_in[3];
  const float* b0  = (const float*)d_in[4];
  const float* W1  = (const float*)d_in[5];
  const float* g1  = (const float*)d_in[6];
  const float* b1  = (const float*)d_in[7];
  const float* W2  = (const float*)d_in[8];
  const float* g2  = (const float*)d_in[9];
  const float* b2  = (const float*)d_in[10];
  float* out = (float*)d_out;

  u16* bqStore = (u16*)d_ws;             // 1 MB in ws (<=1.1 MB proven writable)
  float* sums0 = out + 49152;            // O1 scratch, restored by copy_xyz
  float* sums1 = out + 49152 + 128;
  float* sums2 = out + 49152 + 256;      // 256 floats
  float* part  = out + 98304;            // O2 scratch (524288 floats)
  float* part2 = out + 622592;           // O2 scratch (16384 floats)
  float* out3  = out + 2195456;
  float* out2  = out + 98304;

  fps_kernel<<<8, 1024, 0, stream>>>(xyz, out);
  bq_kernel<<<4096, 256, 0, stream>>>(xyz, out3, bqStore);
  stageA_kernel<<<2048, 128, 0, stream>>>(xyz, pts, W0, out3, bqStore, part);
  red1<<<64, 256, 0, stream>>>(part, part2, 128);
  red2<<<1, 256, 0, stream>>>(part2, sums0, 128);
  stageB_kernel<<<2048, 128, 0, stream>>>(xyz, pts, W0, W1, out3, bqStore,
                                          sums0, g0, b0, part);
  red1<<<64, 256, 0, stream>>>(part, part2, 128);
  red2<<<1, 256, 0, stream>>>(part2, sums1, 128);
  stageC_kernel<<<2048, 128, 0, stream>>>(xyz, pts, W0, W1, W2, out3, bqStore,
                                          sums0, g0, b0, sums1, g1, b1, part);
  red1<<<64, 256, 0, stream>>>(part, part2, 256);
  red2<<<1, 256, 0, stream>>>(part2, sums2, 256);
  stageD_kernel<<<16384, 128, 0, stream>>>(xyz, pts, W0, W1, W2, out3, bqStore,
                                           sums0, g0, b0, sums1, g1, b1,
                                           sums2, g2, b2, out2);
  copy_xyz<<<192, 256, 0, stream>>>(out, out + 49152);
}

// Round 14
// 4960.971 us; speedup vs baseline: 2.9147x; 1.2507x over previous
//
#include <hip/hip_runtime.h>

typedef unsigned short u16;
typedef unsigned int u32;
typedef unsigned long long u64;

#define NPTS 8192
#define SPTS 2048
#define KNS 32
#define MTOTF 524288.0f   // 8*2048*32

// ---- d_out FLOAT32, 2,211,840 elems ----
// O0 [0,49152) new_xyz | O1 [49152,98304) dup (sums scratch; restored by copy)
// O2 [98304,2195456) new_points (part/part2 scratch; stageD overwrites) | O3 [2195456,..) fps_idx
// ws: bqStore u16[524288] (1 MB, proven) + optional ptsT (fp32 16.8 MB / bf16 8.4 MB)

__device__ __forceinline__ float bf2f(u16 u) { return __uint_as_float(((u32)u) << 16); }
__device__ __forceinline__ u16 f2bf(float f) {
  u32 u = __float_as_uint(f);
  return (u16)((u + 0x7FFFu + ((u >> 16) & 1u)) >> 16);
}

// ================================================================ FPS
// 1 block/batch, 512 threads; no global ops in loop (hist in LDS); 1 barrier/iter.
__global__ __launch_bounds__(512) void fps_kernel(const float* __restrict__ xyz,
                                                  float* __restrict__ out) {
  __shared__ float4 hist[SPTS];   // 32 KB
  __shared__ u64 red[2][8];
  const int b = blockIdx.x, tid = threadIdx.x;
  const float* xp = xyz + (size_t)b * 3 * NPTS;
  float X[16], Y[16], Z[16], D[16];
#pragma unroll
  for (int j = 0; j < 16; ++j) {
    int n = j * 512 + tid;
    X[j] = xp[n]; Y[j] = xp[NPTS + n]; Z[j] = xp[2 * NPTS + n];
    D[j] = 1e10f;
  }
  int far = 0;
  for (int i = 0; i < SPTS; ++i) {
    float px = xp[far], py = xp[NPTS + far], pz = xp[2 * NPTS + far];
    if (tid == 0) hist[i] = make_float4(px, py, pz, (float)far);
    u64 best = 0;
#pragma unroll
    for (int j = 0; j < 16; ++j) {
      int n = j * 512 + tid;
      float dx = __fsub_rn(X[j], px), dy = __fsub_rn(Y[j], py), dz = __fsub_rn(Z[j], pz);
      float d = __fadd_rn(__fadd_rn(__fmul_rn(dx, dx), __fmul_rn(dy, dy)), __fmul_rn(dz, dz));
      float dm = fminf(D[j], d);
      D[j] = dm;
      u64 key = ((u64)__float_as_uint(dm) << 32) | (unsigned)(8191 - n);
      best = key > best ? key : best;
    }
#pragma unroll
    for (int off = 32; off >= 1; off >>= 1) {
      u64 o = __shfl_xor(best, off);
      best = o > best ? o : best;
    }
    if ((tid & 63) == 0) red[i & 1][tid >> 6] = best;
    __syncthreads();
    u64 bb = red[i & 1][0];
#pragma unroll
    for (int w = 1; w < 8; ++w) { u64 o = red[i & 1][w]; bb = o > bb ? o : bb; }
    far = (8191 - (int)(unsigned)(bb & 0xffffffffu)) & 8191;
  }
  __syncthreads();
  for (int i = tid; i < SPTS; i += 512) {
    float4 h = hist[i];
    out[(b * 3 + 0) * SPTS + i] = h.x;
    out[(b * 3 + 1) * SPTS + i] = h.y;
    out[(b * 3 + 2) * SPTS + i] = h.z;
    out[2195456 + b * SPTS + i] = h.w;
  }
}

// ================================================================ ball query (once)
__global__ __launch_bounds__(256) void bq_kernel(const float* __restrict__ xyz,
                                                 const float* __restrict__ out3,
                                                 u16* __restrict__ bqStore) {
  const int wid = blockIdx.x * 4 + (threadIdx.x >> 6);
  const int lane = threadIdx.x & 63;
  const int b = wid >> 11;
  const int ctr = ((int)out3[wid]) & 8191;
  const float* xp = xyz + (size_t)b * 3 * NPTS;
  const float cx = xp[ctr], cy = xp[NPTS + ctr], cz = xp[2 * NPTS + ctr];
  int cnt = 0, first = 0;
  bool hf = false;
  for (int ch = 0; ch < NPTS / 64; ++ch) {
    int n = ch * 64 + lane;
    float dx = __fsub_rn(xp[n], cx);
    float dy = __fsub_rn(xp[NPTS + n], cy);
    float dz = __fsub_rn(xp[2 * NPTS + n], cz);
    float d2 = __fadd_rn(__fadd_rn(__fmul_rn(dx, dx), __fmul_rn(dy, dy)), __fmul_rn(dz, dz));
    bool inb = (d2 <= 0.25f);
    u64 m = __ballot(inb);
    if (m) {
      if (!hf) { first = ch * 64 + (__ffsll((unsigned long long)m) - 1); hf = true; }
      int pos = cnt + (int)__popcll(m & ((1ull << lane) - 1ull));
      if (inb && pos < KNS) bqStore[(size_t)wid * KNS + pos] = (u16)n;
      cnt += (int)__popcll(m);
      if (cnt >= KNS) break;
    }
  }
  if (cnt < KNS) {
    int slot = cnt + lane;
    if (slot < KNS) bqStore[(size_t)wid * KNS + slot] = (u16)first;
  }
}

// ================================================================ transposes
__global__ __launch_bounds__(256) void ptsT_f32(const float* __restrict__ pts,
                                                float* __restrict__ ptsT) {
  __shared__ float tile[64][65];
  const int b = blockIdx.x >> 7, n0 = (blockIdx.x & 127) * 64, tid = threadIdx.x;
  {
    int nn = tid & 63;
#pragma unroll
    for (int p = 0; p < 16; ++p) {
      int c = p * 4 + (tid >> 6);
      tile[c][nn] = pts[((size_t)(b * 64 + c)) * NPTS + n0 + nn];
    }
  }
  __syncthreads();
  {
    int c = tid & 63;
#pragma unroll
    for (int p = 0; p < 16; ++p) {
      int nn = p * 4 + (tid >> 6);
      ptsT[((size_t)(b * NPTS) + n0 + nn) * 64 + c] = tile[c][nn];
    }
  }
}
__global__ __launch_bounds__(256) void ptsT_b16(const float* __restrict__ pts,
                                                u16* __restrict__ ptsTh) {
  __shared__ float tile[64][65];
  const int b = blockIdx.x >> 7, n0 = (blockIdx.x & 127) * 64, tid = threadIdx.x;
  {
    int nn = tid & 63;
#pragma unroll
    for (int p = 0; p < 16; ++p) {
      int c = p * 4 + (tid >> 6);
      tile[c][nn] = pts[((size_t)(b * 64 + c)) * NPTS + n0 + nn];
    }
  }
  __syncthreads();
  {
    int c = tid & 63;
#pragma unroll
    for (int p = 0; p < 16; ++p) {
      int nn = p * 4 + (tid >> 6);
      ptsTh[((size_t)(b * NPTS) + n0 + nn) * 64 + c] = f2bf(tile[c][nn]);
    }
  }
}

// ================================================================ helpers
__device__ __forceinline__ void load_w0(const float* __restrict__ W0, float* wbuf, int tid) {
  for (int i = tid; i < 64 * 131; i += 128) {
    int o = i / 131, c = i - o * 131;
    float w = W0[i];
    if (c < 67) wbuf[o * 69 + c] = w;
    else        wbuf[4416 + o * 65 + (c - 67)] = w;
  }
}
__device__ __forceinline__ void load_w(const float* __restrict__ W, float* wbuf,
                                       int tid, int rows) {
  for (int i = tid; i < rows * 64; i += 128) wbuf[(i >> 6) * 65 + (i & 63)] = W[i];
}

__device__ __forceinline__ void gather_m(const float* __restrict__ xyz,
                                         const float* __restrict__ pts,
                                         const float* __restrict__ ptsT,
                                         const u16* __restrict__ ptsTh, int mode,
                                         const int* gidx, int b, int ctr,
                                         float* featb, float* cf, int tid) {
  const float* xp = xyz + (size_t)b * 3 * NPTS;
  if (tid < KNS) {
    int idx = gidx[tid];
    featb[tid * 69 + 0] = __fsub_rn(xp[idx], xp[ctr]);
    featb[tid * 69 + 1] = __fsub_rn(xp[NPTS + idx], xp[NPTS + ctr]);
    featb[tid * 69 + 2] = __fsub_rn(xp[2 * NPTS + idx], xp[2 * NPTS + ctr]);
  }
  const int k = tid >> 2, q = tid & 3;
  if (mode == 2) {
    const float4* base = (const float4*)(ptsT + ((size_t)(b * NPTS) + gidx[k]) * 64 + q * 16);
#pragma unroll
    for (int j = 0; j < 4; ++j) {
      float4 v = base[j];
      featb[k * 69 + 3 + q * 16 + j * 4 + 0] = v.x;
      featb[k * 69 + 3 + q * 16 + j * 4 + 1] = v.y;
      featb[k * 69 + 3 + q * 16 + j * 4 + 2] = v.z;
      featb[k * 69 + 3 + q * 16 + j * 4 + 3] = v.w;
    }
    if (tid < 64) cf[tid] = ptsT[((size_t)(b * NPTS) + ctr) * 64 + tid];
  } else if (mode == 1) {
    const u32* base = (const u32*)(ptsTh + ((size_t)(b * NPTS) + gidx[k]) * 64 + q * 16);
#pragma unroll
    for (int j = 0; j < 8; ++j) {
      u32 w = base[j];
      featb[k * 69 + 3 + q * 16 + j * 2 + 0] = bf2f((u16)(w & 0xFFFFu));
      featb[k * 69 + 3 + q * 16 + j * 2 + 1] = bf2f((u16)(w >> 16));
    }
    if (tid < 64) cf[tid] = bf2f(ptsTh[((size_t)(b * NPTS) + ctr) * 64 + tid]);
  } else {
    const float* base = pts + ((size_t)b * 64 + q * 16) * NPTS + gidx[k];
#pragma unroll
    for (int e = 0; e < 16; ++e)
      featb[k * 69 + 3 + q * 16 + e] = base[(size_t)e * NPTS];
    if (tid < 64) cf[tid] = pts[((size_t)b * 64 + tid) * NPTS + ctr];
  }
}

__device__ __forceinline__ void mm_pre0(const float* featb, const float* cf,
                                        const float* wbuf, int tid, float acc[4][4]) {
  const int o0 = (tid & 15) * 4, k0 = (tid >> 4) * 4;
  float cd[4] = {0.f, 0.f, 0.f, 0.f};
  for (int c = 0; c < 64; ++c) {
    float f = cf[c];
#pragma unroll
    for (int oo = 0; oo < 4; ++oo) cd[oo] += wbuf[4416 + (o0 + oo) * 65 + c] * f;
  }
#pragma unroll
  for (int kk = 0; kk < 4; ++kk)
#pragma unroll
    for (int oo = 0; oo < 4; ++oo) acc[kk][oo] = cd[oo];
  for (int c = 0; c < 67; ++c) {
    float w0 = wbuf[(o0 + 0) * 69 + c], w1 = wbuf[(o0 + 1) * 69 + c];
    float w2 = wbuf[(o0 + 2) * 69 + c], w3 = wbuf[(o0 + 3) * 69 + c];
#pragma unroll
    for (int kk = 0; kk < 4; ++kk) {
      float f = featb[(k0 + kk) * 69 + c];
      acc[kk][0] += w0 * f; acc[kk][1] += w1 * f; acc[kk][2] += w2 * f; acc[kk][3] += w3 * f;
    }
  }
}

__device__ __forceinline__ void mm64(const float* actb, const float* wbuf,
                                     int tid, float acc[4][4]) {
  const int o0 = (tid & 15) * 4, k0 = (tid >> 4) * 4;
#pragma unroll
  for (int kk = 0; kk < 4; ++kk)
#pragma unroll
    for (int oo = 0; oo < 4; ++oo) acc[kk][oo] = 0.f;
  for (int c = 0; c < 64; ++c) {
    float w0 = wbuf[(o0 + 0) * 65 + c], w1 = wbuf[(o0 + 1) * 65 + c];
    float w2 = wbuf[(o0 + 2) * 65 + c], w3 = wbuf[(o0 + 3) * 65 + c];
#pragma unroll
    for (int kk = 0; kk < 4; ++kk) {
      float f = actb[(k0 + kk) * 65 + c];
      acc[kk][0] += w0 * f; acc[kk][1] += w1 * f; acc[kk][2] += w2 * f; acc[kk][3] += w3 * f;
    }
  }
}

__device__ __forceinline__ void bn_consts(const float* __restrict__ sums,
                                          const float* __restrict__ g, const float* __restrict__ b,
                                          float* sc, float* sh, int tid) {
  if (tid < 64) {
    const float invM = 1.0f / MTOTF;
    float mu = sums[tid] * invM;
    float var = fmaxf(sums[64 + tid] * invM - mu * mu, 0.f);
    float inv = rsqrtf(var + 1e-5f);
    float gg = g[tid], bb = b[tid];
    sc[tid] = gg * inv;
    sh[tid] = bb - gg * mu * inv;
  }
}

__device__ __forceinline__ void merge64(float s[4], float q[4], float (*sred)[64],
                                        float (*qred)[64], float* __restrict__ part,
                                        int blk, int tid) {
  const int o0 = (tid & 15) * 4;
#pragma unroll
  for (int m = 16; m <= 32; m <<= 1)
#pragma unroll
    for (int oo = 0; oo < 4; ++oo) {
      s[oo] += __shfl_xor(s[oo], m);
      q[oo] += __shfl_xor(q[oo], m);
    }
  if ((tid & 48) == 0) {
    int wv = tid >> 6;
#pragma unroll
    for (int oo = 0; oo < 4; ++oo) { sred[wv][o0 + oo] = s[oo]; qred[wv][o0 + oo] = q[oo]; }
  }
  __syncthreads();
  if (tid < 64) {
    part[(size_t)blk * 128 + tid] = sred[0][tid] + sred[1][tid];
    part[(size_t)blk * 128 + 64 + tid] = qred[0][tid] + qred[1][tid];
  }
}

// ================================================================ stage A
__global__ __launch_bounds__(128) void stageA_kernel(
    const float* __restrict__ xyz, const float* __restrict__ pts,
    const float* __restrict__ ptsT, const u16* __restrict__ ptsTh, int mode,
    const float* __restrict__ W0,
    const float* __restrict__ out3, const u16* __restrict__ bqStore, float* __restrict__ part) {
  __shared__ float wbuf[8576];
  __shared__ float featb[2208];
  __shared__ float cf[64];
  __shared__ float sred[2][64], qred[2][64];
  __shared__ int gidx[KNS];
  __shared__ int ctrS;
  const int tid = threadIdx.x;
  float s[4] = {0, 0, 0, 0}, q[4] = {0, 0, 0, 0};
  load_w0(W0, wbuf, tid);
  for (int it = 0; it < 8; ++it) {
    int bs = blockIdx.x * 8 + it, b = bs >> 11;
    __syncthreads();
    if (tid < KNS) gidx[tid] = bqStore[(size_t)bs * KNS + tid];
    if (tid == 127) ctrS = ((int)out3[bs]) & 8191;
    __syncthreads();
    gather_m(xyz, pts, ptsT, ptsTh, mode, gidx, b, ctrS, featb, cf, tid);
    __syncthreads();
    float acc[4][4];
    mm_pre0(featb, cf, wbuf, tid, acc);
#pragma unroll
    for (int kk = 0; kk < 4; ++kk)
#pragma unroll
      for (int oo = 0; oo < 4; ++oo) { float v = acc[kk][oo]; s[oo] += v; q[oo] += v * v; }
  }
  merge64(s, q, sred, qred, part, blockIdx.x, tid);
}

// ================================================================ stage B
__global__ __launch_bounds__(128) void stageB_kernel(
    const float* __restrict__ xyz, const float* __restrict__ pts,
    const float* __restrict__ ptsT, const u16* __restrict__ ptsTh, int mode,
    const float* __restrict__ W0, const float* __restrict__ W1,
    const float* __restrict__ out3, const u16* __restrict__ bqStore,
    const float* __restrict__ sums0, const float* __restrict__ g0, const float* __restrict__ b0,
    float* __restrict__ part) {
  __shared__ float wbuf[8576];
  __shared__ float featb[2208];
  __shared__ float cf[64];
  __shared__ float sc0[64], sh0[64];
  __shared__ float sred[2][64], qred[2][64];
  __shared__ int gidx[KNS];
  __shared__ int ctrS;
  const int tid = threadIdx.x;
  float s[4] = {0, 0, 0, 0}, q[4] = {0, 0, 0, 0};
  bn_consts(sums0, g0, b0, sc0, sh0, tid);
  const int o0 = (tid & 15) * 4, k0 = (tid >> 4) * 4;
  for (int it = 0; it < 8; ++it) {
    int bs = blockIdx.x * 8 + it, b = bs >> 11;
    __syncthreads();
    if (tid < KNS) gidx[tid] = bqStore[(size_t)bs * KNS + tid];
    if (tid == 127) ctrS = ((int)out3[bs]) & 8191;
    load_w0(W0, wbuf, tid);
    __syncthreads();
    gather_m(xyz, pts, ptsT, ptsTh, mode, gidx, b, ctrS, featb, cf, tid);
    __syncthreads();
    float acc[4][4];
    mm_pre0(featb, cf, wbuf, tid, acc);
    __syncthreads();
#pragma unroll
    for (int kk = 0; kk < 4; ++kk)
#pragma unroll
      for (int oo = 0; oo < 4; ++oo)
        featb[(k0 + kk) * 65 + o0 + oo] = fmaxf(sc0[o0 + oo] * acc[kk][oo] + sh0[o0 + oo], 0.f);
    load_w(W1, wbuf, tid, 64);
    __syncthreads();
    float acc2[4][4];
    mm64(featb, wbuf, tid, acc2);
#pragma unroll
    for (int kk = 0; kk < 4; ++kk)
#pragma unroll
      for (int oo = 0; oo < 4; ++oo) { float v = acc2[kk][oo]; s[oo] += v; q[oo] += v * v; }
  }
  merge64(s, q, sred, qred, part, blockIdx.x, tid);
}

// ================================================================ stage C
__global__ __launch_bounds__(128) void stageC_kernel(
    const float* __restrict__ xyz, const float* __restrict__ pts,
    const float* __restrict__ ptsT, const u16* __restrict__ ptsTh, int mode,
    const float* __restrict__ W0, const float* __restrict__ W1, const float* __restrict__ W2,
    const float* __restrict__ out3, const u16* __restrict__ bqStore,
    const float* __restrict__ sums0, const float* __restrict__ g0, const float* __restrict__ b0,
    const float* __restrict__ sums1, const float* __restrict__ g1, const float* __restrict__ b1,
    float* __restrict__ part) {
  __shared__ float wbuf[8576];
  __shared__ float featb[2208];
  __shared__ float cf[64];
  __shared__ float sc0[64], sh0[64], sc1[64], sh1[64];
  __shared__ float sred[2][128], qred[2][128];
  __shared__ int gidx[KNS];
  __shared__ int ctrS;
  const int tid = threadIdx.x;
  float s[4] = {0, 0, 0, 0}, q[4] = {0, 0, 0, 0};
  bn_consts(sums0, g0, b0, sc0, sh0, tid);
  bn_consts(sums1, g1, b1, sc1, sh1, tid);
  const int o0 = (tid & 15) * 4, k0 = (tid >> 4) * 4;
  const int p0 = (tid & 31) * 4, kq0 = (tid >> 5) * 8;
  for (int it = 0; it < 8; ++it) {
    int bs = blockIdx.x * 8 + it, b = bs >> 11;
    __syncthreads();
    if (tid < KNS) gidx[tid] = bqStore[(size_t)bs * KNS + tid];
    if (tid == 127) ctrS = ((int)out3[bs]) & 8191;
    load_w0(W0, wbuf, tid);
    __syncthreads();
    gather_m(xyz, pts, ptsT, ptsTh, mode, gidx, b, ctrS, featb, cf, tid);
    __syncthreads();
    float acc[4][4];
    mm_pre0(featb, cf, wbuf, tid, acc);
    __syncthreads();
#pragma unroll
    for (int kk = 0; kk < 4; ++kk)
#pragma unroll
      for (int oo = 0; oo < 4; ++oo)
        featb[(k0 + kk) * 65 + o0 + oo] = fmaxf(sc0[o0 + oo] * acc[kk][oo] + sh0[o0 + oo], 0.f);
    load_w(W1, wbuf, tid, 64);
    __syncthreads();
    float acc2[4][4];
    mm64(featb, wbuf, tid, acc2);
    __syncthreads();
#pragma unroll
    for (int kk = 0; kk < 4; ++kk)
#pragma unroll
      for (int oo = 0; oo < 4; ++oo)
        featb[(k0 + kk) * 65 + o0 + oo] = fmaxf(sc1[o0 + oo] * acc2[kk][oo] + sh1[o0 + oo], 0.f);
    load_w(W2, wbuf, tid, 128);
    __syncthreads();
    float acc3[8][4];
#pragma unroll
    for (int kk = 0; kk < 8; ++kk)
#pragma unroll
      for (int oo = 0; oo < 4; ++oo) acc3[kk][oo] = 0.f;
    for (int c = 0; c < 64; ++c) {
      float w0 = wbuf[(p0 + 0) * 65 + c], w1 = wbuf[(p0 + 1) * 65 + c];
      float w2v = wbuf[(p0 + 2) * 65 + c], w3 = wbuf[(p0 + 3) * 65 + c];
#pragma unroll
      for (int kk = 0; kk < 8; ++kk) {
        float f = featb[(kq0 + kk) * 65 + c];
        acc3[kk][0] += w0 * f; acc3[kk][1] += w1 * f; acc3[kk][2] += w2v * f; acc3[kk][3] += w3 * f;
      }
    }
#pragma unroll
    for (int oo = 0; oo < 4; ++oo)
#pragma unroll
      for (int kk = 0; kk < 8; ++kk) { float v = acc3[kk][oo]; s[oo] += v; q[oo] += v * v; }
  }
#pragma unroll
  for (int oo = 0; oo < 4; ++oo) {
    s[oo] += __shfl_xor(s[oo], 32);
    q[oo] += __shfl_xor(q[oo], 32);
  }
  if ((tid & 32) == 0) {
    int wv = tid >> 6;
#pragma unroll
    for (int oo = 0; oo < 4; ++oo) { sred[wv][p0 + oo] = s[oo]; qred[wv][p0 + oo] = q[oo]; }
  }
  __syncthreads();
  part[(size_t)blockIdx.x * 256 + tid] = sred[0][tid] + sred[1][tid];
  part[(size_t)blockIdx.x * 256 + 128 + tid] = qred[0][tid] + qred[1][tid];
}

// ================================================================ stage D
__global__ __launch_bounds__(128) void stageD_kernel(
    const float* __restrict__ xyz, const float* __restrict__ pts,
    const float* __restrict__ ptsT, const u16* __restrict__ ptsTh, int mode,
    const float* __restrict__ W0, const float* __restrict__ W1, const float* __restrict__ W2,
    const float* __restrict__ out3, const u16* __restrict__ bqStore,
    const float* __restrict__ sums0, const float* __restrict__ g0, const float* __restrict__ b0,
    const float* __restrict__ sums1, const float* __restrict__ g1, const float* __restrict__ b1,
    const float* __restrict__ sums2, const float* __restrict__ g2, const float* __restrict__ b2,
    float* __restrict__ out2) {
  __shared__ float wbuf[8576];
  __shared__ float featb[2208];
  __shared__ float cf[64];
  __shared__ float sc0[64], sh0[64], sc1[64], sh1[64];
  __shared__ float mxred[2][128], mnred[2][128];
  __shared__ int gidx[KNS];
  __shared__ int ctrS;
  const int bs = blockIdx.x, b = bs >> 11, sIdx = bs & 2047, tid = threadIdx.x;
  bn_consts(sums0, g0, b0, sc0, sh0, tid);
  bn_consts(sums1, g1, b1, sc1, sh1, tid);
  if (tid < KNS) gidx[tid] = bqStore[(size_t)bs * KNS + tid];
  if (tid == 127) ctrS = ((int)out3[bs]) & 8191;
  load_w0(W0, wbuf, tid);
  __syncthreads();
  gather_m(xyz, pts, ptsT, ptsTh, mode, gidx, b, ctrS, featb, cf, tid);
  __syncthreads();
  float acc[4][4];
  mm_pre0(featb, cf, wbuf, tid, acc);
  __syncthreads();
  const int o0 = (tid & 15) * 4, k0 = (tid >> 4) * 4;
#pragma unroll
  for (int kk = 0; kk < 4; ++kk)
#pragma unroll
    for (int oo = 0; oo < 4; ++oo)
      featb[(k0 + kk) * 65 + o0 + oo] = fmaxf(sc0[o0 + oo] * acc[kk][oo] + sh0[o0 + oo], 0.f);
  load_w(W1, wbuf, tid, 64);
  __syncthreads();
  float acc2[4][4];
  mm64(featb, wbuf, tid, acc2);
  __syncthreads();
#pragma unroll
  for (int kk = 0; kk < 4; ++kk)
#pragma unroll
    for (int oo = 0; oo < 4; ++oo)
      featb[(k0 + kk) * 65 + o0 + oo] = fmaxf(sc1[o0 + oo] * acc2[kk][oo] + sh1[o0 + oo], 0.f);
  load_w(W2, wbuf, tid, 128);
  __syncthreads();
  const int p0 = (tid & 31) * 4, kq0 = (tid >> 5) * 8;
  float acc3[8][4];
#pragma unroll
  for (int kk = 0; kk < 8; ++kk)
#pragma unroll
    for (int oo = 0; oo < 4; ++oo) acc3[kk][oo] = 0.f;
  for (int c = 0; c < 64; ++c) {
    float w0 = wbuf[(p0 + 0) * 65 + c], w1 = wbuf[(p0 + 1) * 65 + c];
    float w2v = wbuf[(p0 + 2) * 65 + c], w3 = wbuf[(p0 + 3) * 65 + c];
#pragma unroll
    for (int kk = 0; kk < 8; ++kk) {
      float f = featb[(kq0 + kk) * 65 + c];
      acc3[kk][0] += w0 * f; acc3[kk][1] += w1 * f; acc3[kk][2] += w2v * f; acc3[kk][3] += w3 * f;
    }
  }
  float mx[4], mn[4];
#pragma unroll
  for (int oo = 0; oo < 4; ++oo) {
    float a = -3.4e38f, i2 = 3.4e38f;
#pragma unroll
    for (int kk = 0; kk < 8; ++kk) {
      float v = acc3[kk][oo];
      a = fmaxf(a, v); i2 = fminf(i2, v);
    }
    mx[oo] = a; mn[oo] = i2;
  }
#pragma unroll
  for (int oo = 0; oo < 4; ++oo) {
    mx[oo] = fmaxf(mx[oo], __shfl_xor(mx[oo], 32));
    mn[oo] = fminf(mn[oo], __shfl_xor(mn[oo], 32));
  }
  if ((tid & 32) == 0) {
    int wv = tid >> 6;
#pragma unroll
    for (int oo = 0; oo < 4; ++oo) { mxred[wv][p0 + oo] = mx[oo]; mnred[wv][p0 + oo] = mn[oo]; }
  }
  __syncthreads();
  {
    float vmx = fmaxf(mxred[0][tid], mxred[1][tid]);
    float vmn = fminf(mnred[0][tid], mnred[1][tid]);
    const float invM = 1.0f / MTOTF;
    float mu = sums2[tid] * invM;
    float var = fmaxf(sums2[128 + tid] * invM - mu * mu, 0.f);
    float inv = rsqrtf(var + 1e-5f);
    float g = g2[tid], bb = b2[tid];
    float v = (g >= 0.f) ? vmx : vmn;
    float r = g * (v - mu) * inv + bb;
    r = fminf(fmaxf(r, 0.f), 100.f);
    out2[((size_t)(b * 128 + tid)) * SPTS + sIdx] = r;
  }
}

// ================================================================ reductions
__global__ void red1(const float* __restrict__ part, float* __restrict__ part2, int W) {
  const int tid = threadIdx.x;
  if (tid >= W) return;
  float a = 0.f;
  size_t r0 = (size_t)blockIdx.x * 32;
  for (int r = 0; r < 32; ++r) a += part[(r0 + r) * W + tid];
  part2[(size_t)blockIdx.x * W + tid] = a;
}
__global__ void red2(const float* __restrict__ part2, float* __restrict__ sums, int W) {
  const int tid = threadIdx.x;
  if (tid >= W) return;
  float a = 0.f;
  for (int j = 0; j < 64; ++j) a += part2[(size_t)j * W + tid];
  sums[tid] = a;
}

// ================================================================ final copy O0 -> O1
__global__ __launch_bounds__(256) void copy_xyz(const float* __restrict__ src,
                                                float* __restrict__ dst) {
  int i = blockIdx.x * 256 + threadIdx.x;   // 49152
  dst[i] = src[i];
}

// ================================================================ launcher
extern "C" void kernel_launch(void* const* d_in, const int* in_sizes, int n_in,
                              void* d_out, int out_size, void* d_ws, size_t ws_size,
                              hipStream_t stream) {
  (void)in_sizes; (void)n_in; (void)out_size;
  const float* xyz = (const float*)d_in[0];
  const float* pts = (const float*)d_in[1];
  const float* W0  = (const float*)d_in[2];
  const float* g0  = (const float*)d_in[3];
  const float* b0  = (const float*)d_in[4];
  const float* W1  = (const float*)d_in[5];
  const float* g1  = (const float*)d_in[6];
  const float* b1  = (const float*)d_in[7];
  const float* W2  = (const float*)d_in[8];
  const float* g2  = (const float*)d_in[9];
  const float* b2  = (const float*)d_in[10];
  float* out = (float*)d_out;

  u16*   bqStore = (u16*)d_ws;                         // 1 MB (proven by round 13)
  float* ptsT    = (float*)((char*)d_ws + 1048576);
  u16*   ptsTh   = (u16*) ((char*)d_ws + 1048576);
  int mode = 0;
  if (ws_size >= 1048576 + 16777216)      mode = 2;    // fp32 ptsT
  else if (ws_size >= 1048576 + 8388608)  mode = 1;    // bf16 ptsT

  float* sums0 = out + 49152;
  float* sums1 = out + 49152 + 128;
  float* sums2 = out + 49152 + 256;
  float* part  = out + 98304;
  float* part2 = out + 622592;
  float* out3  = out + 2195456;
  float* out2  = out + 98304;

  fps_kernel<<<8, 512, 0, stream>>>(xyz, out);
  if (mode == 2)      ptsT_f32<<<1024, 256, 0, stream>>>(pts, ptsT);
  else if (mode == 1) ptsT_b16<<<1024, 256, 0, stream>>>(pts, ptsTh);
  bq_kernel<<<4096, 256, 0, stream>>>(xyz, out3, bqStore);
  stageA_kernel<<<2048, 128, 0, stream>>>(xyz, pts, ptsT, ptsTh, mode, W0, out3, bqStore, part);
  red1<<<64, 256, 0, stream>>>(part, part2, 128);
  red2<<<1, 256, 0, stream>>>(part2, sums0, 128);
  stageB_kernel<<<2048, 128, 0, stream>>>(xyz, pts, ptsT, ptsTh, mode, W0, W1, out3, bqStore,
                                          sums0, g0, b0, part);
  red1<<<64, 256, 0, stream>>>(part, part2, 128);
  red2<<<1, 256, 0, stream>>>(part2, sums1, 128);
  stageC_kernel<<<2048, 128, 0, stream>>>(xyz, pts, ptsT, ptsTh, mode, W0, W1, W2, out3, bqStore,
                                          sums0, g0, b0, sums1, g1, b1, part);
  red1<<<64, 256, 0, stream>>>(part, part2, 256);
  red2<<<1, 256, 0, stream>>>(part2, sums2, 256);
  stageD_kernel<<<16384, 128, 0, stream>>>(xyz, pts, ptsT, ptsTh, mode, W0, W1, W2, out3, bqStore,
                                           sums0, g0, b0, sums1, g1, b1,
                                           sums2, g2, b2, out2);
  copy_xyz<<<192, 256, 0, stream>>>(out, out + 49152);
}

// Round 15
// 3856.111 us; speedup vs baseline: 3.7499x; 1.2865x over previous
//
#include <hip/hip_runtime.h>

typedef unsigned short u16;
typedef unsigned int u32;
typedef unsigned long long u64;
typedef float f4 __attribute__((ext_vector_type(4)));

#define NPTS 8192
#define SPTS 2048
#define KNS 32
#define MTOTF 524288.0f

// ---- d_out FLOAT32 ----
// O0 [0,49152) new_xyz | O1 [49152,98304) dup (sums scratch; restored by copy)
// O2 [98304,2195456) new_points (part/part2 scratch) | O3 [2195456,..) fps_idx
// ws: [0,1M) bq u16 | [1M,1.08M) WT weights transposed | [1.08M,..) ptsT f32/bf16
#define WT_OFF_F 262144          // float index of WT in ws (byte 1048576)
#define PT_OFF_B 1131520ull      // byte offset of ptsT

__device__ __forceinline__ float bf2f(u16 u) { return __uint_as_float(((u32)u) << 16); }
__device__ __forceinline__ u16 f2bf(float f) {
  u32 u = __float_as_uint(f);
  return (u16)((u + 0x7FFFu + ((u >> 16) & 1u)) >> 16);
}
__device__ __forceinline__ f4 ld4(const float* p) { return *(const f4*)p; }
__device__ __forceinline__ void st4(float* p, f4 v) { *(f4*)p = v; }

// ================================================================ FPS (256 thr)
__global__ __launch_bounds__(256, 1) void fps_kernel(const float* __restrict__ xyz,
                                                     float* __restrict__ out) {
  __shared__ float4 hist[SPTS];   // 32 KB
  __shared__ u64 red[2][4];
  const int b = blockIdx.x, tid = threadIdx.x;
  const float* xp = xyz + (size_t)b * 3 * NPTS;
  float X[32], Y[32], Z[32], D[32];
#pragma unroll
  for (int j = 0; j < 32; ++j) {
    int n = j * 256 + tid;
    X[j] = xp[n]; Y[j] = xp[NPTS + n]; Z[j] = xp[2 * NPTS + n];
    D[j] = 1e10f;
  }
  int far = 0;
  for (int i = 0; i < SPTS; ++i) {
    float px = xp[far], py = xp[NPTS + far], pz = xp[2 * NPTS + far];
    if (tid == 0) hist[i] = make_float4(px, py, pz, (float)far);
    u64 best = 0;
#pragma unroll
    for (int j = 0; j < 32; ++j) {
      int n = j * 256 + tid;
      float dx = __fsub_rn(X[j], px), dy = __fsub_rn(Y[j], py), dz = __fsub_rn(Z[j], pz);
      float d = __fadd_rn(__fadd_rn(__fmul_rn(dx, dx), __fmul_rn(dy, dy)), __fmul_rn(dz, dz));
      float dm = fminf(D[j], d);
      D[j] = dm;
      u64 key = ((u64)__float_as_uint(dm) << 32) | (unsigned)(8191 - n);
      best = key > best ? key : best;
    }
#pragma unroll
    for (int off = 32; off >= 1; off >>= 1) {
      u64 o = __shfl_xor(best, off);
      best = o > best ? o : best;
    }
    if ((tid & 63) == 0) red[i & 1][tid >> 6] = best;
    __syncthreads();
    u64 bb = red[i & 1][0];
#pragma unroll
    for (int w = 1; w < 4; ++w) { u64 o = red[i & 1][w]; bb = o > bb ? o : bb; }
    far = (8191 - (int)(unsigned)(bb & 0xffffffffu)) & 8191;
  }
  __syncthreads();
  for (int i = tid; i < SPTS; i += 256) {
    float4 h = hist[i];
    out[(b * 3 + 0) * SPTS + i] = h.x;
    out[(b * 3 + 1) * SPTS + i] = h.y;
    out[(b * 3 + 2) * SPTS + i] = h.z;
    out[2195456 + b * SPTS + i] = h.w;
  }
}

// ================================================================ ball query
__global__ __launch_bounds__(256) void bq_kernel(const float* __restrict__ xyz,
                                                 const float* __restrict__ out3,
                                                 u16* __restrict__ bqStore) {
  const int wid = blockIdx.x * 4 + (threadIdx.x >> 6);
  const int lane = threadIdx.x & 63;
  const int b = wid >> 11;
  const int ctr = ((int)out3[wid]) & 8191;
  const float* xp = xyz + (size_t)b * 3 * NPTS;
  const float cx = xp[ctr], cy = xp[NPTS + ctr], cz = xp[2 * NPTS + ctr];
  int cnt = 0, first = 0;
  bool hf = false;
  for (int ch = 0; ch < NPTS / 64; ++ch) {
    int n = ch * 64 + lane;
    float dx = __fsub_rn(xp[n], cx);
    float dy = __fsub_rn(xp[NPTS + n], cy);
    float dz = __fsub_rn(xp[2 * NPTS + n], cz);
    float d2 = __fadd_rn(__fadd_rn(__fmul_rn(dx, dx), __fmul_rn(dy, dy)), __fmul_rn(dz, dz));
    bool inb = (d2 <= 0.25f);
    u64 m = __ballot(inb);
    if (m) {
      if (!hf) { first = ch * 64 + (__ffsll((unsigned long long)m) - 1); hf = true; }
      int pos = cnt + (int)__popcll(m & ((1ull << lane) - 1ull));
      if (inb && pos < KNS) bqStore[(size_t)wid * KNS + pos] = (u16)n;
      cnt += (int)__popcll(m);
      if (cnt >= KNS) break;
    }
  }
  if (cnt < KNS) {
    int slot = cnt + lane;
    if (slot < KNS) bqStore[(size_t)wid * KNS + slot] = (u16)first;
  }
}

// ================================================================ weight transpose prep
// WT layout (float idx): [0,4352) W0mT c(68)xo(64)  (c=3 zero row)
//                        [4352,8448) W0cT 64x64 | [8448,12544) W1T 64x64
//                        [12544,20736) W2T c(64)xo(128)
__global__ __launch_bounds__(256) void wt_prep(const float* __restrict__ W0,
                                               const float* __restrict__ W1,
                                               const float* __restrict__ W2,
                                               float* __restrict__ WT) {
  int i = blockIdx.x * 256 + threadIdx.x;
  if (i < 4352) {
    int c = i >> 6, o = i & 63;
    WT[i] = (c < 3) ? W0[o * 131 + c] : (c == 3 ? 0.f : W0[o * 131 + c - 1]);
  } else if (i < 8448) {
    int j = i - 4352, c = j >> 6, o = j & 63;
    WT[i] = W0[o * 131 + 67 + c];
  } else if (i < 12544) {
    int j = i - 8448, c = j >> 6, o = j & 63;
    WT[i] = W1[o * 64 + c];
  } else if (i < 20736) {
    int j = i - 12544, c = j >> 7, o = j & 127;
    WT[i] = W2[o * 64 + c];
  }
}

// ================================================================ transposes (pts)
__global__ __launch_bounds__(256) void ptsT_f32(const float* __restrict__ pts,
                                                float* __restrict__ ptsT) {
  __shared__ float tile[64][65];
  const int b = blockIdx.x >> 7, n0 = (blockIdx.x & 127) * 64, tid = threadIdx.x;
  {
    int nn = tid & 63;
#pragma unroll
    for (int p = 0; p < 16; ++p) {
      int c = p * 4 + (tid >> 6);
      tile[c][nn] = pts[((size_t)(b * 64 + c)) * NPTS + n0 + nn];
    }
  }
  __syncthreads();
  {
    int c = tid & 63;
#pragma unroll
    for (int p = 0; p < 16; ++p) {
      int nn = p * 4 + (tid >> 6);
      ptsT[((size_t)(b * NPTS) + n0 + nn) * 64 + c] = tile[c][nn];
    }
  }
}
__global__ __launch_bounds__(256) void ptsT_b16(const float* __restrict__ pts,
                                                u16* __restrict__ ptsTh) {
  __shared__ float tile[64][65];
  const int b = blockIdx.x >> 7, n0 = (blockIdx.x & 127) * 64, tid = threadIdx.x;
  {
    int nn = tid & 63;
#pragma unroll
    for (int p = 0; p < 16; ++p) {
      int c = p * 4 + (tid >> 6);
      tile[c][nn] = pts[((size_t)(b * 64 + c)) * NPTS + n0 + nn];
    }
  }
  __syncthreads();
  {
    int c = tid & 63;
#pragma unroll
    for (int p = 0; p < 16; ++p) {
      int nn = p * 4 + (tid >> 6);
      ptsTh[((size_t)(b * NPTS) + n0 + nn) * 64 + c] = f2bf(tile[c][nn]);
    }
  }
}

// ================================================================ stage helpers
// featb: [32][68], cols: 0..2 rel_xyz, 3 = 0, 4..67 = pts channels. Acts reuse rows (cols 0..63).
__device__ __forceinline__ void load_w0(const float* __restrict__ WT, float* wbuf, int tid) {
  for (int i = tid * 4; i < 8448; i += 512) st4(wbuf + i, ld4(WT + i));
}
__device__ __forceinline__ void load_w1(const float* __restrict__ WT, float* wbuf, int tid) {
  for (int i = tid * 4; i < 4096; i += 512) st4(wbuf + i, ld4(WT + 8448 + i));
}
__device__ __forceinline__ void load_w2(const float* __restrict__ WT, float* wbuf, int tid) {
  for (int i = tid * 4; i < 8192; i += 512) st4(wbuf + i, ld4(WT + 12544 + i));
}

__device__ __forceinline__ void gather_m(const float* __restrict__ xyz,
                                         const float* __restrict__ pts,
                                         const float* __restrict__ ptsT,
                                         const u16* __restrict__ ptsTh, int mode,
                                         const int* gidx, int b, int ctr,
                                         float* featb, float* cf, int tid) {
  const float* xp = xyz + (size_t)b * 3 * NPTS;
  if (tid < KNS) {
    int idx = gidx[tid];
    featb[tid * 68 + 0] = __fsub_rn(xp[idx], xp[ctr]);
    featb[tid * 68 + 1] = __fsub_rn(xp[NPTS + idx], xp[NPTS + ctr]);
    featb[tid * 68 + 2] = __fsub_rn(xp[2 * NPTS + idx], xp[2 * NPTS + ctr]);
    featb[tid * 68 + 3] = 0.f;
  }
  const int k = tid >> 2, q = tid & 3;
  if (mode == 2) {
    const f4* base = (const f4*)(ptsT + ((size_t)(b * NPTS) + gidx[k]) * 64 + q * 16);
#pragma unroll
    for (int j = 0; j < 4; ++j) st4(featb + k * 68 + 4 + q * 16 + 4 * j, base[j]);
    if (tid < 64) cf[tid] = ptsT[((size_t)(b * NPTS) + ctr) * 64 + tid];
  } else if (mode == 1) {
    const uint2* base = (const uint2*)(ptsTh + ((size_t)(b * NPTS) + gidx[k]) * 64 + q * 16);
#pragma unroll
    for (int j = 0; j < 4; ++j) {
      uint2 w = base[j];
      f4 v;
      v.x = bf2f((u16)(w.x & 0xFFFFu)); v.y = bf2f((u16)(w.x >> 16));
      v.z = bf2f((u16)(w.y & 0xFFFFu)); v.w = bf2f((u16)(w.y >> 16));
      st4(featb + k * 68 + 4 + q * 16 + 4 * j, v);
    }
    if (tid < 64) cf[tid] = bf2f(ptsTh[((size_t)(b * NPTS) + ctr) * 64 + tid]);
  } else {
    const float* base = pts + ((size_t)b * 64 + q * 16) * NPTS + gidx[k];
#pragma unroll
    for (int e = 0; e < 16; ++e)
      featb[k * 68 + 4 + q * 16 + e] = base[(size_t)e * NPTS];
    if (tid < 64) cf[tid] = pts[((size_t)b * 64 + tid) * NPTS + ctr];
  }
}

// pre0: acc[kk] = f4 over 4 consecutive o at o0=(tid&15)*4, k tile k0=(tid>>4)*4
__device__ __forceinline__ void mm_pre0(const float* featb, const float* cf,
                                        const float* wbuf, int tid, f4 acc[4]) {
  const int o0 = (tid & 15) * 4, k0 = (tid >> 4) * 4;
  const float* wc = wbuf + 4352;
  f4 cd = {0.f, 0.f, 0.f, 0.f};
  for (int c = 0; c < 64; c += 4) {
    f4 cfv = ld4(cf + c);
    cd += ld4(wc + (c + 0) * 64 + o0) * cfv.x;
    cd += ld4(wc + (c + 1) * 64 + o0) * cfv.y;
    cd += ld4(wc + (c + 2) * 64 + o0) * cfv.z;
    cd += ld4(wc + (c + 3) * 64 + o0) * cfv.w;
  }
  acc[0] = cd; acc[1] = cd; acc[2] = cd; acc[3] = cd;
  for (int c = 0; c < 68; c += 4) {
    f4 w0 = ld4(wbuf + (c + 0) * 64 + o0), w1 = ld4(wbuf + (c + 1) * 64 + o0);
    f4 w2 = ld4(wbuf + (c + 2) * 64 + o0), w3 = ld4(wbuf + (c + 3) * 64 + o0);
#pragma unroll
    for (int kk = 0; kk < 4; ++kk) {
      f4 f = ld4(featb + (k0 + kk) * 68 + c);
      acc[kk] += w0 * f.x + w1 * f.y + w2 * f.z + w3 * f.w;
    }
  }
}

__device__ __forceinline__ void mm64(const float* actb, const float* wbuf,
                                     int tid, f4 acc[4]) {
  const int o0 = (tid & 15) * 4, k0 = (tid >> 4) * 4;
  f4 z = {0.f, 0.f, 0.f, 0.f};
  acc[0] = z; acc[1] = z; acc[2] = z; acc[3] = z;
  for (int c = 0; c < 64; c += 4) {
    f4 w0 = ld4(wbuf + (c + 0) * 64 + o0), w1 = ld4(wbuf + (c + 1) * 64 + o0);
    f4 w2 = ld4(wbuf + (c + 2) * 64 + o0), w3 = ld4(wbuf + (c + 3) * 64 + o0);
#pragma unroll
    for (int kk = 0; kk < 4; ++kk) {
      f4 f = ld4(actb + (k0 + kk) * 68 + c);
      acc[kk] += w0 * f.x + w1 * f.y + w2 * f.z + w3 * f.w;
    }
  }
}

__device__ __forceinline__ f4 relu4(f4 v) {
  f4 r;
  r.x = fmaxf(v.x, 0.f); r.y = fmaxf(v.y, 0.f);
  r.z = fmaxf(v.z, 0.f); r.w = fmaxf(v.w, 0.f);
  return r;
}

__device__ __forceinline__ void bn_consts(const float* __restrict__ sums,
                                          const float* __restrict__ g, const float* __restrict__ b,
                                          float* sc, float* sh, int tid) {
  if (tid < 64) {
    const float invM = 1.0f / MTOTF;
    float mu = sums[tid] * invM;
    float var = fmaxf(sums[64 + tid] * invM - mu * mu, 0.f);
    float inv = rsqrtf(var + 1e-5f);
    float gg = g[tid], bb = b[tid];
    sc[tid] = gg * inv;
    sh[tid] = bb - gg * mu * inv;
  }
}

__device__ __forceinline__ void merge64(f4 s4, f4 q4, float (*sred)[64],
                                        float (*qred)[64], float* __restrict__ part,
                                        int blk, int tid) {
  const int o0 = (tid & 15) * 4;
  float s[4] = {s4.x, s4.y, s4.z, s4.w};
  float q[4] = {q4.x, q4.y, q4.z, q4.w};
#pragma unroll
  for (int m = 16; m <= 32; m <<= 1)
#pragma unroll
    for (int oo = 0; oo < 4; ++oo) {
      s[oo] += __shfl_xor(s[oo], m);
      q[oo] += __shfl_xor(q[oo], m);
    }
  if ((tid & 48) == 0) {
    int wv = tid >> 6;
#pragma unroll
    for (int oo = 0; oo < 4; ++oo) { sred[wv][o0 + oo] = s[oo]; qred[wv][o0 + oo] = q[oo]; }
  }
  __syncthreads();
  if (tid < 64) {
    part[(size_t)blk * 128 + tid] = sred[0][tid] + sred[1][tid];
    part[(size_t)blk * 128 + 64 + tid] = qred[0][tid] + qred[1][tid];
  }
}

// ================================================================ stage A
__global__ __launch_bounds__(128) void stageA_kernel(
    const float* __restrict__ xyz, const float* __restrict__ pts,
    const float* __restrict__ ptsT, const u16* __restrict__ ptsTh, int mode,
    const float* __restrict__ WT,
    const float* __restrict__ out3, const u16* __restrict__ bqStore, float* __restrict__ part) {
  __shared__ float wbuf[8448];
  __shared__ float featb[2176];
  __shared__ float cf[64];
  __shared__ float sred[2][64], qred[2][64];
  __shared__ int gidx[KNS];
  __shared__ int ctrS;
  const int tid = threadIdx.x;
  f4 s = {0.f, 0.f, 0.f, 0.f}, q = {0.f, 0.f, 0.f, 0.f};
  load_w0(WT, wbuf, tid);
  for (int it = 0; it < 8; ++it) {
    int bs = blockIdx.x * 8 + it, b = bs >> 11;
    __syncthreads();
    if (tid < KNS) gidx[tid] = bqStore[(size_t)bs * KNS + tid];
    if (tid == 127) ctrS = ((int)out3[bs]) & 8191;
    __syncthreads();
    gather_m(xyz, pts, ptsT, ptsTh, mode, gidx, b, ctrS, featb, cf, tid);
    __syncthreads();
    f4 acc[4];
    mm_pre0(featb, cf, wbuf, tid, acc);
#pragma unroll
    for (int kk = 0; kk < 4; ++kk) { s += acc[kk]; q += acc[kk] * acc[kk]; }
  }
  merge64(s, q, sred, qred, part, blockIdx.x, tid);
}

// ================================================================ stage B
__global__ __launch_bounds__(128) void stageB_kernel(
    const float* __restrict__ xyz, const float* __restrict__ pts,
    const float* __restrict__ ptsT, const u16* __restrict__ ptsTh, int mode,
    const float* __restrict__ WT,
    const float* __restrict__ out3, const u16* __restrict__ bqStore,
    const float* __restrict__ sums0, const float* __restrict__ g0, const float* __restrict__ b0,
    float* __restrict__ part) {
  __shared__ float wbuf[8448];
  __shared__ float featb[2176];
  __shared__ float cf[64];
  __shared__ float sc0[64], sh0[64];
  __shared__ float sred[2][64], qred[2][64];
  __shared__ int gidx[KNS];
  __shared__ int ctrS;
  const int tid = threadIdx.x;
  const int o0 = (tid & 15) * 4, k0 = (tid >> 4) * 4;
  f4 s = {0.f, 0.f, 0.f, 0.f}, q = {0.f, 0.f, 0.f, 0.f};
  bn_consts(sums0, g0, b0, sc0, sh0, tid);
  for (int it = 0; it < 8; ++it) {
    int bs = blockIdx.x * 8 + it, b = bs >> 11;
    __syncthreads();
    if (tid < KNS) gidx[tid] = bqStore[(size_t)bs * KNS + tid];
    if (tid == 127) ctrS = ((int)out3[bs]) & 8191;
    __syncthreads();
    load_w0(WT, wbuf, tid);
    gather_m(xyz, pts, ptsT, ptsTh, mode, gidx, b, ctrS, featb, cf, tid);
    __syncthreads();
    f4 acc[4];
    mm_pre0(featb, cf, wbuf, tid, acc);
    __syncthreads();
    f4 scv = ld4(sc0 + o0), shv = ld4(sh0 + o0);
#pragma unroll
    for (int kk = 0; kk < 4; ++kk)
      st4(featb + (k0 + kk) * 68 + o0, relu4(scv * acc[kk] + shv));
    load_w1(WT, wbuf, tid);
    __syncthreads();
    f4 acc2[4];
    mm64(featb, wbuf, tid, acc2);
#pragma unroll
    for (int kk = 0; kk < 4; ++kk) { s += acc2[kk]; q += acc2[kk] * acc2[kk]; }
  }
  merge64(s, q, sred, qred, part, blockIdx.x, tid);
}

// ================================================================ stage C
__global__ __launch_bounds__(128) void stageC_kernel(
    const float* __restrict__ xyz, const float* __restrict__ pts,
    const float* __restrict__ ptsT, const u16* __restrict__ ptsTh, int mode,
    const float* __restrict__ WT,
    const float* __restrict__ out3, const u16* __restrict__ bqStore,
    const float* __restrict__ sums0, const float* __restrict__ g0, const float* __restrict__ b0,
    const float* __restrict__ sums1, const float* __restrict__ g1, const float* __restrict__ b1,
    float* __restrict__ part) {
  __shared__ float wbuf[8448];
  __shared__ float featb[2176];
  __shared__ float cf[64];
  __shared__ float sc0[64], sh0[64], sc1[64], sh1[64];
  __shared__ float sred[2][128], qred[2][128];
  __shared__ int gidx[KNS];
  __shared__ int ctrS;
  const int tid = threadIdx.x;
  const int o0 = (tid & 15) * 4, k0 = (tid >> 4) * 4;
  const int p0 = (tid & 31) * 4, kq0 = (tid >> 5) * 8;
  f4 s = {0.f, 0.f, 0.f, 0.f}, q = {0.f, 0.f, 0.f, 0.f};
  bn_consts(sums0, g0, b0, sc0, sh0, tid);
  bn_consts(sums1, g1, b1, sc1, sh1, tid);
  for (int it = 0; it < 8; ++it) {
    int bs = blockIdx.x * 8 + it, b = bs >> 11;
    __syncthreads();
    if (tid < KNS) gidx[tid] = bqStore[(size_t)bs * KNS + tid];
    if (tid == 127) ctrS = ((int)out3[bs]) & 8191;
    __syncthreads();
    load_w0(WT, wbuf, tid);
    gather_m(xyz, pts, ptsT, ptsTh, mode, gidx, b, ctrS, featb, cf, tid);
    __syncthreads();
    f4 acc[4];
    mm_pre0(featb, cf, wbuf, tid, acc);
    __syncthreads();
    {
      f4 scv = ld4(sc0 + o0), shv = ld4(sh0 + o0);
#pragma unroll
      for (int kk = 0; kk < 4; ++kk)
        st4(featb + (k0 + kk) * 68 + o0, relu4(scv * acc[kk] + shv));
    }
    load_w1(WT, wbuf, tid);
    __syncthreads();
    f4 acc2[4];
    mm64(featb, wbuf, tid, acc2);
    __syncthreads();
    {
      f4 scv = ld4(sc1 + o0), shv = ld4(sh1 + o0);
#pragma unroll
      for (int kk = 0; kk < 4; ++kk)
        st4(featb + (k0 + kk) * 68 + o0, relu4(scv * acc2[kk] + shv));
    }
    load_w2(WT, wbuf, tid);
    __syncthreads();
    f4 a3[8];
    f4 z = {0.f, 0.f, 0.f, 0.f};
#pragma unroll
    for (int kk = 0; kk < 8; ++kk) a3[kk] = z;
    for (int c = 0; c < 64; c += 4) {
      f4 w0 = ld4(wbuf + (c + 0) * 128 + p0), w1 = ld4(wbuf + (c + 1) * 128 + p0);
      f4 w2 = ld4(wbuf + (c + 2) * 128 + p0), w3 = ld4(wbuf + (c + 3) * 128 + p0);
#pragma unroll
      for (int kk = 0; kk < 8; ++kk) {
        f4 f = ld4(featb + (kq0 + kk) * 68 + c);
        a3[kk] += w0 * f.x + w1 * f.y + w2 * f.z + w3 * f.w;
      }
    }
#pragma unroll
    for (int kk = 0; kk < 8; ++kk) { s += a3[kk]; q += a3[kk] * a3[kk]; }
  }
  {
    float sa[4] = {s.x, s.y, s.z, s.w}, qa[4] = {q.x, q.y, q.z, q.w};
#pragma unroll
    for (int oo = 0; oo < 4; ++oo) {
      sa[oo] += __shfl_xor(sa[oo], 32);
      qa[oo] += __shfl_xor(qa[oo], 32);
    }
    if ((tid & 32) == 0) {
      int wv = tid >> 6;
#pragma unroll
      for (int oo = 0; oo < 4; ++oo) { sred[wv][p0 + oo] = sa[oo]; qred[wv][p0 + oo] = qa[oo]; }
    }
  }
  __syncthreads();
  part[(size_t)blockIdx.x * 256 + tid] = sred[0][tid] + sred[1][tid];
  part[(size_t)blockIdx.x * 256 + 128 + tid] = qred[0][tid] + qred[1][tid];
}

// ================================================================ stage D
__global__ __launch_bounds__(128) void stageD_kernel(
    const float* __restrict__ xyz, const float* __restrict__ pts,
    const float* __restrict__ ptsT, const u16* __restrict__ ptsTh, int mode,
    const float* __restrict__ WT,
    const float* __restrict__ out3, const u16* __restrict__ bqStore,
    const float* __restrict__ sums0, const float* __restrict__ g0, const float* __restrict__ b0,
    const float* __restrict__ sums1, const float* __restrict__ g1, const float* __restrict__ b1,
    const float* __restrict__ sums2, const float* __restrict__ g2, const float* __restrict__ b2,
    float* __restrict__ out2) {
  __shared__ float wbuf[8448];
  __shared__ float featb[2176];
  __shared__ float cf[64];
  __shared__ float sc0[64], sh0[64], sc1[64], sh1[64];
  __shared__ float mxred[2][128], mnred[2][128];
  __shared__ int gidx[KNS];
  __shared__ int ctrS;
  const int bs = blockIdx.x, b = bs >> 11, sIdx = bs & 2047, tid = threadIdx.x;
  const int o0 = (tid & 15) * 4, k0 = (tid >> 4) * 4;
  const int p0 = (tid & 31) * 4, kq0 = (tid >> 5) * 8;
  bn_consts(sums0, g0, b0, sc0, sh0, tid);
  bn_consts(sums1, g1, b1, sc1, sh1, tid);
  if (tid < KNS) gidx[tid] = bqStore[(size_t)bs * KNS + tid];
  if (tid == 127) ctrS = ((int)out3[bs]) & 8191;
  __syncthreads();
  load_w0(WT, wbuf, tid);
  gather_m(xyz, pts, ptsT, ptsTh, mode, gidx, b, ctrS, featb, cf, tid);
  __syncthreads();
  f4 acc[4];
  mm_pre0(featb, cf, wbuf, tid, acc);
  __syncthreads();
  {
    f4 scv = ld4(sc0 + o0), shv = ld4(sh0 + o0);
#pragma unroll
    for (int kk = 0; kk < 4; ++kk)
      st4(featb + (k0 + kk) * 68 + o0, relu4(scv * acc[kk] + shv));
  }
  load_w1(WT, wbuf, tid);
  __syncthreads();
  f4 acc2[4];
  mm64(featb, wbuf, tid, acc2);
  __syncthreads();
  {
    f4 scv = ld4(sc1 + o0), shv = ld4(sh1 + o0);
#pragma unroll
    for (int kk = 0; kk < 4; ++kk)
      st4(featb + (k0 + kk) * 68 + o0, relu4(scv * acc2[kk] + shv));
  }
  load_w2(WT, wbuf, tid);
  __syncthreads();
  f4 a3[8];
  f4 z = {0.f, 0.f, 0.f, 0.f};
#pragma unroll
  for (int kk = 0; kk < 8; ++kk) a3[kk] = z;
  for (int c = 0; c < 64; c += 4) {
    f4 w0 = ld4(wbuf + (c + 0) * 128 + p0), w1 = ld4(wbuf + (c + 1) * 128 + p0);
    f4 w2 = ld4(wbuf + (c + 2) * 128 + p0), w3 = ld4(wbuf + (c + 3) * 128 + p0);
#pragma unroll
    for (int kk = 0; kk < 8; ++kk) {
      f4 f = ld4(featb + (kq0 + kk) * 68 + c);
      a3[kk] += w0 * f.x + w1 * f.y + w2 * f.z + w3 * f.w;
    }
  }
  float mx[4], mn[4];
#pragma unroll
  for (int oo = 0; oo < 4; ++oo) { mx[oo] = -3.4e38f; mn[oo] = 3.4e38f; }
#pragma unroll
  for (int kk = 0; kk < 8; ++kk) {
    float v[4] = {a3[kk].x, a3[kk].y, a3[kk].z, a3[kk].w};
#pragma unroll
    for (int oo = 0; oo < 4; ++oo) { mx[oo] = fmaxf(mx[oo], v[oo]); mn[oo] = fminf(mn[oo], v[oo]); }
  }
#pragma unroll
  for (int oo = 0; oo < 4; ++oo) {
    mx[oo] = fmaxf(mx[oo], __shfl_xor(mx[oo], 32));
    mn[oo] = fminf(mn[oo], __shfl_xor(mn[oo], 32));
  }
  if ((tid & 32) == 0) {
    int wv = tid >> 6;
#pragma unroll
    for (int oo = 0; oo < 4; ++oo) { mxred[wv][p0 + oo] = mx[oo]; mnred[wv][p0 + oo] = mn[oo]; }
  }
  __syncthreads();
  {
    float vmx = fmaxf(mxred[0][tid], mxred[1][tid]);
    float vmn = fminf(mnred[0][tid], mnred[1][tid]);
    const float invM = 1.0f / MTOTF;
    float mu = sums2[tid] * invM;
    float var = fmaxf(sums2[128 + tid] * invM - mu * mu, 0.f);
    float inv = rsqrtf(var + 1e-5f);
    float g = g2[tid], bb = b2[tid];
    float v = (g >= 0.f) ? vmx : vmn;
    float r = g * (v - mu) * inv + bb;
    r = fminf(fmaxf(r, 0.f), 100.f);
    out2[((size_t)(b * 128 + tid)) * SPTS + sIdx] = r;
  }
}

// ================================================================ reductions
__global__ void red1(const float* __restrict__ part, float* __restrict__ part2, int W) {
  const int tid = threadIdx.x;
  if (tid >= W) return;
  float a = 0.f;
  size_t r0 = (size_t)blockIdx.x * 32;
  for (int r = 0; r < 32; ++r) a += part[(r0 + r) * W + tid];
  part2[(size_t)blockIdx.x * W + tid] = a;
}
__global__ void red2(const float* __restrict__ part2, float* __restrict__ sums, int W) {
  const int tid = threadIdx.x;
  if (tid >= W) return;
  float a = 0.f;
  for (int j = 0; j < 64; ++j) a += part2[(size_t)j * W + tid];
  sums[tid] = a;
}

// ================================================================ final copy
__global__ __launch_bounds__(256) void copy_xyz(const float* __restrict__ src,
                                                float* __restrict__ dst) {
  int i = blockIdx.x * 256 + threadIdx.x;
  dst[i] = src[i];
}

// ================================================================ launcher
extern "C" void kernel_launch(void* const* d_in, const int* in_sizes, int n_in,
                              void* d_out, int out_size, void* d_ws, size_t ws_size,
                              hipStream_t stream) {
  (void)in_sizes; (void)n_in; (void)out_size;
  const float* xyz = (const float*)d_in[0];
  const float* pts = (const float*)d_in[1];
  const float* W0  = (const float*)d_in[2];
  const float* g0  = (const float*)d_in[3];
  const float* b0  = (const float*)d_in[4];
  const float* W1  = (const float*)d_in[5];
  const float* g1  = (const float*)d_in[6];
  const float* b1  = (const float*)d_in[7];
  const float* W2  = (const float*)d_in[8];
  const float* g2  = (const float*)d_in[9];
  const float* b2  = (const float*)d_in[10];
  float* out = (float*)d_out;

  u16*   bqStore = (u16*)d_ws;                       // [0, 1 MB)
  float* WT      = (float*)d_ws + WT_OFF_F;          // [1 MB, 1.08 MB) — 83 KB (ws >= 17.8 MB proven)
  float* ptsT    = (float*)((char*)d_ws + PT_OFF_B);
  u16*   ptsTh   = (u16*) ((char*)d_ws + PT_OFF_B);
  int mode = 0;
  if (ws_size >= PT_OFF_B + 16777216)      mode = 2;  // fp32 ptsT
  else if (ws_size >= PT_OFF_B + 8388608)  mode = 1;  // bf16 ptsT (guaranteed: ws >= 17.8 MB)

  float* sums0 = out + 49152;
  float* sums1 = out + 49152 + 128;
  float* sums2 = out + 49152 + 256;
  float* part  = out + 98304;
  float* part2 = out + 622592;
  float* out3  = out + 2195456;
  float* out2  = out + 98304;

  fps_kernel<<<8, 256, 0, stream>>>(xyz, out);
  wt_prep<<<81, 256, 0, stream>>>(W0, W1, W2, WT);
  if (mode == 2)      ptsT_f32<<<1024, 256, 0, stream>>>(pts, ptsT);
  else if (mode == 1) ptsT_b16<<<1024, 256, 0, stream>>>(pts, ptsTh);
  bq_kernel<<<4096, 256, 0, stream>>>(xyz, out3, bqStore);
  stageA_kernel<<<2048, 128, 0, stream>>>(xyz, pts, ptsT, ptsTh, mode, WT, out3, bqStore, part);
  red1<<<64, 256, 0, stream>>>(part, part2, 128);
  red2<<<1, 256, 0, stream>>>(part2, sums0, 128);
  stageB_kernel<<<2048, 128, 0, stream>>>(xyz, pts, ptsT, ptsTh, mode, WT, out3, bqStore,
                                          sums0, g0, b0, part);
  red1<<<64, 256, 0, stream>>>(part, part2, 128);
  red2<<<1, 256, 0, stream>>>(part2, sums1, 128);
  stageC_kernel<<<2048, 128, 0, stream>>>(xyz, pts, ptsT, ptsTh, mode, WT, out3, bqStore,
                                          sums0, g0, b0, sums1, g1, b1, part);
  red1<<<64, 256, 0, stream>>>(part, part2, 256);
  red2<<<1, 256, 0, stream>>>(part2, sums2, 256);
  stageD_kernel<<<16384, 128, 0, stream>>>(xyz, pts, ptsT, ptsTh, mode, WT, out3, bqStore,
                                           sums0, g0, b0, sums1, g1, b1,
                                           sums2, g2, b2, out2);
  copy_xyz<<<192, 256, 0, stream>>>(out, out + 49152);
}

// Round 16
// 3554.657 us; speedup vs baseline: 4.0679x; 1.0848x over previous
//
#include <hip/hip_runtime.h>

typedef unsigned short u16;
typedef unsigned int u32;
typedef unsigned long long u64;
typedef float f4 __attribute__((ext_vector_type(4)));

#define NPTS 8192
#define SPTS 2048
#define KNS 32
#define MTOTF 524288.0f

// ---- d_out FLOAT32 ----
// O0 [0,49152) new_xyz | O1 [49152,98304) dup (sums scratch; restored by copy)
// O2 [98304,2195456) new_points (part/part2 scratch) | O3 [2195456,..) fps_idx
// ws: [0,1M) bq u16 | [1M,1.08M) WT weights transposed | [1.08M,..) ptsT f32/bf16
#define WT_OFF_F 262144
#define PT_OFF_B 1131520ull

__device__ __forceinline__ float bf2f(u16 u) { return __uint_as_float(((u32)u) << 16); }
__device__ __forceinline__ u16 f2bf(float f) {
  u32 u = __float_as_uint(f);
  return (u16)((u + 0x7FFFu + ((u >> 16) & 1u)) >> 16);
}
__device__ __forceinline__ f4 ld4(const float* p) { return *(const f4*)p; }
__device__ __forceinline__ void st4(float* p, f4 v) { *(f4*)p = v; }

// DPP wave64 max-reduce (u32, nonneg values; identity 0). Result broadcast to all lanes.
#define DPP_MAXSTEP(v, ctrl)                                                        \
  {                                                                                 \
    u32 _t = (u32)__builtin_amdgcn_update_dpp(0, (int)(v), ctrl, 0xf, 0xf, true);   \
    (v) = _t > (v) ? _t : (v);                                                      \
  }
__device__ __forceinline__ u32 wave_max_u32(u32 v) {
  DPP_MAXSTEP(v, 0x111);  // row_shr:1
  DPP_MAXSTEP(v, 0x112);  // row_shr:2
  DPP_MAXSTEP(v, 0x114);  // row_shr:4
  DPP_MAXSTEP(v, 0x118);  // row_shr:8
  DPP_MAXSTEP(v, 0x142);  // row_bcast:15
  DPP_MAXSTEP(v, 0x143);  // row_bcast:31
  return (u32)__builtin_amdgcn_readlane((int)v, 63);
}

// ================================================================ FPS (512 thr, DPP reduce)
__global__ __launch_bounds__(512, 1) void fps_kernel(const float* __restrict__ xyz,
                                                     float* __restrict__ out) {
  __shared__ float4 hist[SPTS];   // 32 KB
  __shared__ u64 red[2][8];
  const int b = blockIdx.x, tid = threadIdx.x;
  const float* xp = xyz + (size_t)b * 3 * NPTS;
  float X[16], Y[16], Z[16], D[16];
#pragma unroll
  for (int j = 0; j < 16; ++j) {
    int n = j * 512 + tid;
    X[j] = xp[n]; Y[j] = xp[NPTS + n]; Z[j] = xp[2 * NPTS + n];
    D[j] = 1e10f;
  }
  int far = 0;
  for (int i = 0; i < SPTS; ++i) {
    float px = xp[far], py = xp[NPTS + far], pz = xp[2 * NPTS + far];
    if (tid == 0) hist[i] = make_float4(px, py, pz, (float)far);
    u64 best = 0;
#pragma unroll
    for (int j = 0; j < 16; ++j) {
      int n = j * 512 + tid;
      float dx = __fsub_rn(X[j], px), dy = __fsub_rn(Y[j], py), dz = __fsub_rn(Z[j], pz);
      float d = __fadd_rn(__fadd_rn(__fmul_rn(dx, dx), __fmul_rn(dy, dy)), __fmul_rn(dz, dz));
      float dm = fminf(D[j], d);
      D[j] = dm;
      u64 key = ((u64)__float_as_uint(dm) << 32) | (unsigned)(8191 - n);
      best = key > best ? key : best;
    }
    // wave reduction via DPP: max on hi (dist bits), then max on lo among hi-winners
    u32 bh = (u32)(best >> 32), bl = (u32)best;
    u32 mh = wave_max_u32(bh);
    u32 cand = (bh == mh) ? bl : 0u;
    u32 ml = wave_max_u32(cand);
    if ((tid & 63) == 0) red[i & 1][tid >> 6] = ((u64)mh << 32) | ml;
    __syncthreads();
    u64 bb = red[i & 1][0];
#pragma unroll
    for (int w = 1; w < 8; ++w) { u64 o = red[i & 1][w]; bb = o > bb ? o : bb; }
    far = (8191 - (int)(unsigned)(bb & 0xffffffffu)) & 8191;
  }
  __syncthreads();
  for (int i = tid; i < SPTS; i += 512) {
    float4 h = hist[i];
    out[(b * 3 + 0) * SPTS + i] = h.x;
    out[(b * 3 + 1) * SPTS + i] = h.y;
    out[(b * 3 + 2) * SPTS + i] = h.z;
    out[2195456 + b * SPTS + i] = h.w;
  }
}

// ================================================================ ball query
__global__ __launch_bounds__(256) void bq_kernel(const float* __restrict__ xyz,
                                                 const float* __restrict__ out3,
                                                 u16* __restrict__ bqStore) {
  const int wid = blockIdx.x * 4 + (threadIdx.x >> 6);
  const int lane = threadIdx.x & 63;
  const int b = wid >> 11;
  const int ctr = ((int)out3[wid]) & 8191;
  const float* xp = xyz + (size_t)b * 3 * NPTS;
  const float cx = xp[ctr], cy = xp[NPTS + ctr], cz = xp[2 * NPTS + ctr];
  int cnt = 0, first = 0;
  bool hf = false;
  for (int ch = 0; ch < NPTS / 64; ++ch) {
    int n = ch * 64 + lane;
    float dx = __fsub_rn(xp[n], cx);
    float dy = __fsub_rn(xp[NPTS + n], cy);
    float dz = __fsub_rn(xp[2 * NPTS + n], cz);
    float d2 = __fadd_rn(__fadd_rn(__fmul_rn(dx, dx), __fmul_rn(dy, dy)), __fmul_rn(dz, dz));
    bool inb = (d2 <= 0.25f);
    u64 m = __ballot(inb);
    if (m) {
      if (!hf) { first = ch * 64 + (__ffsll((unsigned long long)m) - 1); hf = true; }
      int pos = cnt + (int)__popcll(m & ((1ull << lane) - 1ull));
      if (inb && pos < KNS) bqStore[(size_t)wid * KNS + pos] = (u16)n;
      cnt += (int)__popcll(m);
      if (cnt >= KNS) break;
    }
  }
  if (cnt < KNS) {
    int slot = cnt + lane;
    if (slot < KNS) bqStore[(size_t)wid * KNS + slot] = (u16)first;
  }
}

// ================================================================ weight transpose prep
__global__ __launch_bounds__(256) void wt_prep(const float* __restrict__ W0,
                                               const float* __restrict__ W1,
                                               const float* __restrict__ W2,
                                               float* __restrict__ WT) {
  int i = blockIdx.x * 256 + threadIdx.x;
  if (i < 4352) {
    int c = i >> 6, o = i & 63;
    WT[i] = (c < 3) ? W0[o * 131 + c] : (c == 3 ? 0.f : W0[o * 131 + c - 1]);
  } else if (i < 8448) {
    int j = i - 4352, c = j >> 6, o = j & 63;
    WT[i] = W0[o * 131 + 67 + c];
  } else if (i < 12544) {
    int j = i - 8448, c = j >> 6, o = j & 63;
    WT[i] = W1[o * 64 + c];
  } else if (i < 20736) {
    int j = i - 12544, c = j >> 7, o = j & 127;
    WT[i] = W2[o * 64 + c];
  }
}

// ================================================================ transposes (pts)
__global__ __launch_bounds__(256) void ptsT_f32(const float* __restrict__ pts,
                                                float* __restrict__ ptsT) {
  __shared__ float tile[64][65];
  const int b = blockIdx.x >> 7, n0 = (blockIdx.x & 127) * 64, tid = threadIdx.x;
  {
    int nn = tid & 63;
#pragma unroll
    for (int p = 0; p < 16; ++p) {
      int c = p * 4 + (tid >> 6);
      tile[c][nn] = pts[((size_t)(b * 64 + c)) * NPTS + n0 + nn];
    }
  }
  __syncthreads();
  {
    int c = tid & 63;
#pragma unroll
    for (int p = 0; p < 16; ++p) {
      int nn = p * 4 + (tid >> 6);
      ptsT[((size_t)(b * NPTS) + n0 + nn) * 64 + c] = tile[c][nn];
    }
  }
}
__global__ __launch_bounds__(256) void ptsT_b16(const float* __restrict__ pts,
                                                u16* __restrict__ ptsTh) {
  __shared__ float tile[64][65];
  const int b = blockIdx.x >> 7, n0 = (blockIdx.x & 127) * 64, tid = threadIdx.x;
  {
    int nn = tid & 63;
#pragma unroll
    for (int p = 0; p < 16; ++p) {
      int c = p * 4 + (tid >> 6);
      tile[c][nn] = pts[((size_t)(b * 64 + c)) * NPTS + n0 + nn];
    }
  }
  __syncthreads();
  {
    int c = tid & 63;
#pragma unroll
    for (int p = 0; p < 16; ++p) {
      int nn = p * 4 + (tid >> 6);
      ptsTh[((size_t)(b * NPTS) + n0 + nn) * 64 + c] = f2bf(tile[c][nn]);
    }
  }
}

// ================================================================ stage helpers
__device__ __forceinline__ void load_w0(const float* __restrict__ WT, float* wbuf, int tid) {
  for (int i = tid * 4; i < 8448; i += 512) st4(wbuf + i, ld4(WT + i));
}
__device__ __forceinline__ void load_w1(const float* __restrict__ WT, float* wbuf, int tid) {
  for (int i = tid * 4; i < 4096; i += 512) st4(wbuf + i, ld4(WT + 8448 + i));
}
__device__ __forceinline__ void load_w2(const float* __restrict__ WT, float* wbuf, int tid) {
  for (int i = tid * 4; i < 8192; i += 512) st4(wbuf + i, ld4(WT + 12544 + i));
}

__device__ __forceinline__ void gather_m(const float* __restrict__ xyz,
                                         const float* __restrict__ pts,
                                         const float* __restrict__ ptsT,
                                         const u16* __restrict__ ptsTh, int mode,
                                         const int* gidx, int b, int ctr,
                                         float* featb, float* cf, int tid) {
  const float* xp = xyz + (size_t)b * 3 * NPTS;
  if (tid < KNS) {
    int idx = gidx[tid];
    featb[tid * 68 + 0] = __fsub_rn(xp[idx], xp[ctr]);
    featb[tid * 68 + 1] = __fsub_rn(xp[NPTS + idx], xp[NPTS + ctr]);
    featb[tid * 68 + 2] = __fsub_rn(xp[2 * NPTS + idx], xp[2 * NPTS + ctr]);
    featb[tid * 68 + 3] = 0.f;
  }
  const int k = tid >> 2, q = tid & 3;
  if (mode == 2) {
    const f4* base = (const f4*)(ptsT + ((size_t)(b * NPTS) + gidx[k]) * 64 + q * 16);
#pragma unroll
    for (int j = 0; j < 4; ++j) st4(featb + k * 68 + 4 + q * 16 + 4 * j, base[j]);
    if (tid < 64) cf[tid] = ptsT[((size_t)(b * NPTS) + ctr) * 64 + tid];
  } else if (mode == 1) {
    const uint2* base = (const uint2*)(ptsTh + ((size_t)(b * NPTS) + gidx[k]) * 64 + q * 16);
#pragma unroll
    for (int j = 0; j < 4; ++j) {
      uint2 w = base[j];
      f4 v;
      v.x = bf2f((u16)(w.x & 0xFFFFu)); v.y = bf2f((u16)(w.x >> 16));
      v.z = bf2f((u16)(w.y & 0xFFFFu)); v.w = bf2f((u16)(w.y >> 16));
      st4(featb + k * 68 + 4 + q * 16 + 4 * j, v);
    }
    if (tid < 64) cf[tid] = bf2f(ptsTh[((size_t)(b * NPTS) + ctr) * 64 + tid]);
  } else {
    const float* base = pts + ((size_t)b * 64 + q * 16) * NPTS + gidx[k];
#pragma unroll
    for (int e = 0; e < 16; ++e)
      featb[k * 68 + 4 + q * 16 + e] = base[(size_t)e * NPTS];
    if (tid < 64) cf[tid] = pts[((size_t)b * 64 + tid) * NPTS + ctr];
  }
}

__device__ __forceinline__ void mm_pre0(const float* featb, const float* cf,
                                        const float* wbuf, int tid, f4 acc[4]) {
  const int o0 = (tid & 15) * 4, k0 = (tid >> 4) * 4;
  const float* wc = wbuf + 4352;
  f4 cd = {0.f, 0.f, 0.f, 0.f};
  for (int c = 0; c < 64; c += 4) {
    f4 cfv = ld4(cf + c);
    cd += ld4(wc + (c + 0) * 64 + o0) * cfv.x;
    cd += ld4(wc + (c + 1) * 64 + o0) * cfv.y;
    cd += ld4(wc + (c + 2) * 64 + o0) * cfv.z;
    cd += ld4(wc + (c + 3) * 64 + o0) * cfv.w;
  }
  acc[0] = cd; acc[1] = cd; acc[2] = cd; acc[3] = cd;
  for (int c = 0; c < 68; c += 4) {
    f4 w0 = ld4(wbuf + (c + 0) * 64 + o0), w1 = ld4(wbuf + (c + 1) * 64 + o0);
    f4 w2 = ld4(wbuf + (c + 2) * 64 + o0), w3 = ld4(wbuf + (c + 3) * 64 + o0);
#pragma unroll
    for (int kk = 0; kk < 4; ++kk) {
      f4 f = ld4(featb + (k0 + kk) * 68 + c);
      acc[kk] += w0 * f.x + w1 * f.y + w2 * f.z + w3 * f.w;
    }
  }
}

__device__ __forceinline__ void mm64(const float* actb, const float* wbuf,
                                     int tid, f4 acc[4]) {
  const int o0 = (tid & 15) * 4, k0 = (tid >> 4) * 4;
  f4 z = {0.f, 0.f, 0.f, 0.f};
  acc[0] = z; acc[1] = z; acc[2] = z; acc[3] = z;
  for (int c = 0; c < 64; c += 4) {
    f4 w0 = ld4(wbuf + (c + 0) * 64 + o0), w1 = ld4(wbuf + (c + 1) * 64 + o0);
    f4 w2 = ld4(wbuf + (c + 2) * 64 + o0), w3 = ld4(wbuf + (c + 3) * 64 + o0);
#pragma unroll
    for (int kk = 0; kk < 4; ++kk) {
      f4 f = ld4(actb + (k0 + kk) * 68 + c);
      acc[kk] += w0 * f.x + w1 * f.y + w2 * f.z + w3 * f.w;
    }
  }
}

__device__ __forceinline__ f4 relu4(f4 v) {
  f4 r;
  r.x = fmaxf(v.x, 0.f); r.y = fmaxf(v.y, 0.f);
  r.z = fmaxf(v.z, 0.f); r.w = fmaxf(v.w, 0.f);
  return r;
}

__device__ __forceinline__ void bn_consts(const float* __restrict__ sums,
                                          const float* __restrict__ g, const float* __restrict__ b,
                                          float* sc, float* sh, int tid) {
  if (tid < 64) {
    const float invM = 1.0f / MTOTF;
    float mu = sums[tid] * invM;
    float var = fmaxf(sums[64 + tid] * invM - mu * mu, 0.f);
    float inv = rsqrtf(var + 1e-5f);
    float gg = g[tid], bb = b[tid];
    sc[tid] = gg * inv;
    sh[tid] = bb - gg * mu * inv;
  }
}

__device__ __forceinline__ void merge64(f4 s4, f4 q4, float (*sred)[64],
                                        float (*qred)[64], float* __restrict__ part,
                                        int blk, int tid) {
  const int o0 = (tid & 15) * 4;
  float s[4] = {s4.x, s4.y, s4.z, s4.w};
  float q[4] = {q4.x, q4.y, q4.z, q4.w};
#pragma unroll
  for (int m = 16; m <= 32; m <<= 1)
#pragma unroll
    for (int oo = 0; oo < 4; ++oo) {
      s[oo] += __shfl_xor(s[oo], m);
      q[oo] += __shfl_xor(q[oo], m);
    }
  if ((tid & 48) == 0) {
    int wv = tid >> 6;
#pragma unroll
    for (int oo = 0; oo < 4; ++oo) { sred[wv][o0 + oo] = s[oo]; qred[wv][o0 + oo] = q[oo]; }
  }
  __syncthreads();
  if (tid < 64) {
    part[(size_t)blk * 128 + tid] = sred[0][tid] + sred[1][tid];
    part[(size_t)blk * 128 + 64 + tid] = qred[0][tid] + qred[1][tid];
  }
}

// ================================================================ stage A
__global__ __launch_bounds__(128) void stageA_kernel(
    const float* __restrict__ xyz, const float* __restrict__ pts,
    const float* __restrict__ ptsT, const u16* __restrict__ ptsTh, int mode,
    const float* __restrict__ WT,
    const float* __restrict__ out3, const u16* __restrict__ bqStore, float* __restrict__ part) {
  __shared__ float wbuf[8448];
  __shared__ float featb[2176];
  __shared__ float cf[64];
  __shared__ float sred[2][64], qred[2][64];
  __shared__ int gidx[KNS];
  __shared__ int ctrS;
  const int tid = threadIdx.x;
  f4 s = {0.f, 0.f, 0.f, 0.f}, q = {0.f, 0.f, 0.f, 0.f};
  load_w0(WT, wbuf, tid);
  for (int it = 0; it < 8; ++it) {
    int bs = blockIdx.x * 8 + it, b = bs >> 11;
    __syncthreads();
    if (tid < KNS) gidx[tid] = bqStore[(size_t)bs * KNS + tid];
    if (tid == 127) ctrS = ((int)out3[bs]) & 8191;
    __syncthreads();
    gather_m(xyz, pts, ptsT, ptsTh, mode, gidx, b, ctrS, featb, cf, tid);
    __syncthreads();
    f4 acc[4];
    mm_pre0(featb, cf, wbuf, tid, acc);
#pragma unroll
    for (int kk = 0; kk < 4; ++kk) { s += acc[kk]; q += acc[kk] * acc[kk]; }
  }
  merge64(s, q, sred, qred, part, blockIdx.x, tid);
}

// ================================================================ stage B
__global__ __launch_bounds__(128) void stageB_kernel(
    const float* __restrict__ xyz, const float* __restrict__ pts,
    const float* __restrict__ ptsT, const u16* __restrict__ ptsTh, int mode,
    const float* __restrict__ WT,
    const float* __restrict__ out3, const u16* __restrict__ bqStore,
    const float* __restrict__ sums0, const float* __restrict__ g0, const float* __restrict__ b0,
    float* __restrict__ part) {
  __shared__ float wbuf[8448];
  __shared__ float featb[2176];
  __shared__ float cf[64];
  __shared__ float sc0[64], sh0[64];
  __shared__ float sred[2][64], qred[2][64];
  __shared__ int gidx[KNS];
  __shared__ int ctrS;
  const int tid = threadIdx.x;
  const int o0 = (tid & 15) * 4, k0 = (tid >> 4) * 4;
  f4 s = {0.f, 0.f, 0.f, 0.f}, q = {0.f, 0.f, 0.f, 0.f};
  bn_consts(sums0, g0, b0, sc0, sh0, tid);
  for (int it = 0; it < 8; ++it) {
    int bs = blockIdx.x * 8 + it, b = bs >> 11;
    __syncthreads();
    if (tid < KNS) gidx[tid] = bqStore[(size_t)bs * KNS + tid];
    if (tid == 127) ctrS = ((int)out3[bs]) & 8191;
    __syncthreads();
    load_w0(WT, wbuf, tid);
    gather_m(xyz, pts, ptsT, ptsTh, mode, gidx, b, ctrS, featb, cf, tid);
    __syncthreads();
    f4 acc[4];
    mm_pre0(featb, cf, wbuf, tid, acc);
    __syncthreads();
    f4 scv = ld4(sc0 + o0), shv = ld4(sh0 + o0);
#pragma unroll
    for (int kk = 0; kk < 4; ++kk)
      st4(featb + (k0 + kk) * 68 + o0, relu4(scv * acc[kk] + shv));
    load_w1(WT, wbuf, tid);
    __syncthreads();
    f4 acc2[4];
    mm64(featb, wbuf, tid, acc2);
#pragma unroll
    for (int kk = 0; kk < 4; ++kk) { s += acc2[kk]; q += acc2[kk] * acc2[kk]; }
  }
  merge64(s, q, sred, qred, part, blockIdx.x, tid);
}

// ================================================================ stage C
__global__ __launch_bounds__(128) void stageC_kernel(
    const float* __restrict__ xyz, const float* __restrict__ pts,
    const float* __restrict__ ptsT, const u16* __restrict__ ptsTh, int mode,
    const float* __restrict__ WT,
    const float* __restrict__ out3, const u16* __restrict__ bqStore,
    const float* __restrict__ sums0, const float* __restrict__ g0, const float* __restrict__ b0,
    const float* __restrict__ sums1, const float* __restrict__ g1, const float* __restrict__ b1,
    float* __restrict__ part) {
  __shared__ float wbuf[8448];
  __shared__ float featb[2176];
  __shared__ float cf[64];
  __shared__ float sc0[64], sh0[64], sc1[64], sh1[64];
  __shared__ float sred[2][128], qred[2][128];
  __shared__ int gidx[KNS];
  __shared__ int ctrS;
  const int tid = threadIdx.x;
  const int o0 = (tid & 15) * 4, k0 = (tid >> 4) * 4;
  const int p0 = (tid & 31) * 4, kq0 = (tid >> 5) * 8;
  f4 s = {0.f, 0.f, 0.f, 0.f}, q = {0.f, 0.f, 0.f, 0.f};
  bn_consts(sums0, g0, b0, sc0, sh0, tid);
  bn_consts(sums1, g1, b1, sc1, sh1, tid);
  for (int it = 0; it < 8; ++it) {
    int bs = blockIdx.x * 8 + it, b = bs >> 11;
    __syncthreads();
    if (tid < KNS) gidx[tid] = bqStore[(size_t)bs * KNS + tid];
    if (tid == 127) ctrS = ((int)out3[bs]) & 8191;
    __syncthreads();
    load_w0(WT, wbuf, tid);
    gather_m(xyz, pts, ptsT, ptsTh, mode, gidx, b, ctrS, featb, cf, tid);
    __syncthreads();
    f4 acc[4];
    mm_pre0(featb, cf, wbuf, tid, acc);
    __syncthreads();
    {
      f4 scv = ld4(sc0 + o0), shv = ld4(sh0 + o0);
#pragma unroll
      for (int kk = 0; kk < 4; ++kk)
        st4(featb + (k0 + kk) * 68 + o0, relu4(scv * acc[kk] + shv));
    }
    load_w1(WT, wbuf, tid);
    __syncthreads();
    f4 acc2[4];
    mm64(featb, wbuf, tid, acc2);
    __syncthreads();
    {
      f4 scv = ld4(sc1 + o0), shv = ld4(sh1 + o0);
#pragma unroll
      for (int kk = 0; kk < 4; ++kk)
        st4(featb + (k0 + kk) * 68 + o0, relu4(scv * acc2[kk] + shv));
    }
    load_w2(WT, wbuf, tid);
    __syncthreads();
    f4 a3[8];
    f4 z = {0.f, 0.f, 0.f, 0.f};
#pragma unroll
    for (int kk = 0; kk < 8; ++kk) a3[kk] = z;
    for (int c = 0; c < 64; c += 4) {
      f4 w0 = ld4(wbuf + (c + 0) * 128 + p0), w1 = ld4(wbuf + (c + 1) * 128 + p0);
      f4 w2 = ld4(wbuf + (c + 2) * 128 + p0), w3 = ld4(wbuf + (c + 3) * 128 + p0);
#pragma unroll
      for (int kk = 0; kk < 8; ++kk) {
        f4 f = ld4(featb + (kq0 + kk) * 68 + c);
        a3[kk] += w0 * f.x + w1 * f.y + w2 * f.z + w3 * f.w;
      }
    }
#pragma unroll
    for (int kk = 0; kk < 8; ++kk) { s += a3[kk]; q += a3[kk] * a3[kk]; }
  }
  {
    float sa[4] = {s.x, s.y, s.z, s.w}, qa[4] = {q.x, q.y, q.z, q.w};
#pragma unroll
    for (int oo = 0; oo < 4; ++oo) {
      sa[oo] += __shfl_xor(sa[oo], 32);
      qa[oo] += __shfl_xor(qa[oo], 32);
    }
    if ((tid & 32) == 0) {
      int wv = tid >> 6;
#pragma unroll
      for (int oo = 0; oo < 4; ++oo) { sred[wv][p0 + oo] = sa[oo]; qred[wv][p0 + oo] = qa[oo]; }
    }
  }
  __syncthreads();
  part[(size_t)blockIdx.x * 256 + tid] = sred[0][tid] + sred[1][tid];
  part[(size_t)blockIdx.x * 256 + 128 + tid] = qred[0][tid] + qred[1][tid];
}

// ================================================================ stage D
__global__ __launch_bounds__(128) void stageD_kernel(
    const float* __restrict__ xyz, const float* __restrict__ pts,
    const float* __restrict__ ptsT, const u16* __restrict__ ptsTh, int mode,
    const float* __restrict__ WT,
    const float* __restrict__ out3, const u16* __restrict__ bqStore,
    const float* __restrict__ sums0, const float* __restrict__ g0, const float* __restrict__ b0,
    const float* __restrict__ sums1, const float* __restrict__ g1, const float* __restrict__ b1,
    const float* __restrict__ sums2, const float* __restrict__ g2, const float* __restrict__ b2,
    float* __restrict__ out2) {
  __shared__ float wbuf[8448];
  __shared__ float featb[2176];
  __shared__ float cf[64];
  __shared__ float sc0[64], sh0[64], sc1[64], sh1[64];
  __shared__ float mxred[2][128], mnred[2][128];
  __shared__ int gidx[KNS];
  __shared__ int ctrS;
  const int bs = blockIdx.x, b = bs >> 11, sIdx = bs & 2047, tid = threadIdx.x;
  const int o0 = (tid & 15) * 4, k0 = (tid >> 4) * 4;
  const int p0 = (tid & 31) * 4, kq0 = (tid >> 5) * 8;
  bn_consts(sums0, g0, b0, sc0, sh0, tid);
  bn_consts(sums1, g1, b1, sc1, sh1, tid);
  if (tid < KNS) gidx[tid] = bqStore[(size_t)bs * KNS + tid];
  if (tid == 127) ctrS = ((int)out3[bs]) & 8191;
  __syncthreads();
  load_w0(WT, wbuf, tid);
  gather_m(xyz, pts, ptsT, ptsTh, mode, gidx, b, ctrS, featb, cf, tid);
  __syncthreads();
  f4 acc[4];
  mm_pre0(featb, cf, wbuf, tid, acc);
  __syncthreads();
  {
    f4 scv = ld4(sc0 + o0), shv = ld4(sh0 + o0);
#pragma unroll
    for (int kk = 0; kk < 4; ++kk)
      st4(featb + (k0 + kk) * 68 + o0, relu4(scv * acc[kk] + shv));
  }
  load_w1(WT, wbuf, tid);
  __syncthreads();
  f4 acc2[4];
  mm64(featb, wbuf, tid, acc2);
  __syncthreads();
  {
    f4 scv = ld4(sc1 + o0), shv = ld4(sh1 + o0);
#pragma unroll
    for (int kk = 0; kk < 4; ++kk)
      st4(featb + (k0 + kk) * 68 + o0, relu4(scv * acc2[kk] + shv));
  }
  load_w2(WT, wbuf, tid);
  __syncthreads();
  f4 a3[8];
  f4 z = {0.f, 0.f, 0.f, 0.f};
#pragma unroll
  for (int kk = 0; kk < 8; ++kk) a3[kk] = z;
  for (int c = 0; c < 64; c += 4) {
    f4 w0 = ld4(wbuf + (c + 0) * 128 + p0), w1 = ld4(wbuf + (c + 1) * 128 + p0);
    f4 w2 = ld4(wbuf + (c + 2) * 128 + p0), w3 = ld4(wbuf + (c + 3) * 128 + p0);
#pragma unroll
    for (int kk = 0; kk < 8; ++kk) {
      f4 f = ld4(featb + (kq0 + kk) * 68 + c);
      a3[kk] += w0 * f.x + w1 * f.y + w2 * f.z + w3 * f.w;
    }
  }
  float mx[4], mn[4];
#pragma unroll
  for (int oo = 0; oo < 4; ++oo) { mx[oo] = -3.4e38f; mn[oo] = 3.4e38f; }
#pragma unroll
  for (int kk = 0; kk < 8; ++kk) {
    float v[4] = {a3[kk].x, a3[kk].y, a3[kk].z, a3[kk].w};
#pragma unroll
    for (int oo = 0; oo < 4; ++oo) { mx[oo] = fmaxf(mx[oo], v[oo]); mn[oo] = fminf(mn[oo], v[oo]); }
  }
#pragma unroll
  for (int oo = 0; oo < 4; ++oo) {
    mx[oo] = fmaxf(mx[oo], __shfl_xor(mx[oo], 32));
    mn[oo] = fminf(mn[oo], __shfl_xor(mn[oo], 32));
  }
  if ((tid & 32) == 0) {
    int wv = tid >> 6;
#pragma unroll
    for (int oo = 0; oo < 4; ++oo) { mxred[wv][p0 + oo] = mx[oo]; mnred[wv][p0 + oo] = mn[oo]; }
  }
  __syncthreads();
  {
    float vmx = fmaxf(mxred[0][tid], mxred[1][tid]);
    float vmn = fminf(mnred[0][tid], mnred[1][tid]);
    const float invM = 1.0f / MTOTF;
    float mu = sums2[tid] * invM;
    float var = fmaxf(sums2[128 + tid] * invM - mu * mu, 0.f);
    float inv = rsqrtf(var + 1e-5f);
    float g = g2[tid], bb = b2[tid];
    float v = (g >= 0.f) ? vmx : vmn;
    float r = g * (v - mu) * inv + bb;
    r = fminf(fmaxf(r, 0.f), 100.f);
    out2[((size_t)(b * 128 + tid)) * SPTS + sIdx] = r;
  }
}

// ================================================================ reductions
__global__ void red1(const float* __restrict__ part, float* __restrict__ part2, int W) {
  const int tid = threadIdx.x;
  if (tid >= W) return;
  float a = 0.f;
  size_t r0 = (size_t)blockIdx.x * 32;
  for (int r = 0; r < 32; ++r) a += part[(r0 + r) * W + tid];
  part2[(size_t)blockIdx.x * W + tid] = a;
}
__global__ void red2(const float* __restrict__ part2, float* __restrict__ sums, int W) {
  const int tid = threadIdx.x;
  if (tid >= W) return;
  float a = 0.f;
  for (int j = 0; j < 64; ++j) a += part2[(size_t)j * W + tid];
  sums[tid] = a;
}

// ================================================================ final copy
__global__ __launch_bounds__(256) void copy_xyz(const float* __restrict__ src,
                                                float* __restrict__ dst) {
  int i = blockIdx.x * 256 + threadIdx.x;
  dst[i] = src[i];
}

// ================================================================ launcher
extern "C" void kernel_launch(void* const* d_in, const int* in_sizes, int n_in,
                              void* d_out, int out_size, void* d_ws, size_t ws_size,
                              hipStream_t stream) {
  (void)in_sizes; (void)n_in; (void)out_size;
  const float* xyz = (const float*)d_in[0];
  const float* pts = (const float*)d_in[1];
  const float* W0  = (const float*)d_in[2];
  const float* g0  = (const float*)d_in[3];
  const float* b0  = (const float*)d_in[4];
  const float* W1  = (const float*)d_in[5];
  const float* g1  = (const float*)d_in[6];
  const float* b1  = (const float*)d_in[7];
  const float* W2  = (const float*)d_in[8];
  const float* g2  = (const float*)d_in[9];
  const float* b2  = (const float*)d_in[10];
  float* out = (float*)d_out;

  u16*   bqStore = (u16*)d_ws;
  float* WT      = (float*)d_ws + WT_OFF_F;
  float* ptsT    = (float*)((char*)d_ws + PT_OFF_B);
  u16*   ptsTh   = (u16*) ((char*)d_ws + PT_OFF_B);
  int mode = 0;
  if (ws_size >= PT_OFF_B + 16777216)      mode = 2;
  else if (ws_size >= PT_OFF_B + 8388608)  mode = 1;

  float* sums0 = out + 49152;
  float* sums1 = out + 49152 + 128;
  float* sums2 = out + 49152 + 256;
  float* part  = out + 98304;
  float* part2 = out + 622592;
  float* out3  = out + 2195456;
  float* out2  = out + 98304;

  fps_kernel<<<8, 512, 0, stream>>>(xyz, out);
  wt_prep<<<81, 256, 0, stream>>>(W0, W1, W2, WT);
  if (mode == 2)      ptsT_f32<<<1024, 256, 0, stream>>>(pts, ptsT);
  else if (mode == 1) ptsT_b16<<<1024, 256, 0, stream>>>(pts, ptsTh);
  bq_kernel<<<4096, 256, 0, stream>>>(xyz, out3, bqStore);
  stageA_kernel<<<2048, 128, 0, stream>>>(xyz, pts, ptsT, ptsTh, mode, WT, out3, bqStore, part);
  red1<<<64, 256, 0, stream>>>(part, part2, 128);
  red2<<<1, 256, 0, stream>>>(part2, sums0, 128);
  stageB_kernel<<<2048, 128, 0, stream>>>(xyz, pts, ptsT, ptsTh, mode, WT, out3, bqStore,
                                          sums0, g0, b0, part);
  red1<<<64, 256, 0, stream>>>(part, part2, 128);
  red2<<<1, 256, 0, stream>>>(part2, sums1, 128);
  stageC_kernel<<<2048, 128, 0, stream>>>(xyz, pts, ptsT, ptsTh, mode, WT, out3, bqStore,
                                          sums0, g0, b0, sums1, g1, b1, part);
  red1<<<64, 256, 0, stream>>>(part, part2, 256);
  red2<<<1, 256, 0, stream>>>(part2, sums2, 256);
  stageD_kernel<<<16384, 128, 0, stream>>>(xyz, pts, ptsT, ptsTh, mode, WT, out3, bqStore,
                                           sums0, g0, b0, sums1, g1, b1,
                                           sums2, g2, b2, out2);
  copy_xyz<<<192, 256, 0, stream>>>(out, out + 49152);
}